// Round 2
// baseline (4670.264 us; speedup 1.0000x reference)
//
#include <hip/hip_runtime.h>
#include <cstdint>
#include <cstddef>

#define NNODES 30000
#define NEDGES 480000

constexpr unsigned ENC_NEGINF = 0x007FFFFFu;  // encode(-inf)

__device__ __forceinline__ unsigned enc_f32(float f) {
  unsigned u = __float_as_uint(f);
  return (u & 0x80000000u) ? ~u : (u | 0x80000000u);
}
__device__ __forceinline__ float dec_f32(unsigned e) {
  unsigned u = (e & 0x80000000u) ? (e ^ 0x80000000u) : ~e;
  return __uint_as_float(u);
}

__global__ void fill_u32(unsigned* __restrict__ p, int n, unsigned v) {
  int i = blockIdx.x * 256 + threadIdx.x;
  if (i < n) p[i] = v;
}

// Decode encoded max-agg into hcat slice (hc already offset by column).
__global__ void decode_kernel(const unsigned* __restrict__ agg, float* __restrict__ hc,
                              int shift, int total) {
  int i = blockIdx.x * 256 + threadIdx.x;
  if (i < total) {
    unsigned e = agg[i];
    float v = (e == ENC_NEGINF) ? 0.0f : dec_f32(e);
    int r = i >> shift;
    int c = i & ((1 << shift) - 1);
    hc[(size_t)r * 448 + c] = v;
  }
}

// P[n] = x[n] @ (W1_top - W1_bot) + b1 ; Q[n] = x[n] @ W1_bot
// X has leading dim ldx, starting at column koff. Tile: 64 rows x 64 cols.
template <int K, int D>
__global__ __launch_bounds__(256) void pq_kernel(
    const float* __restrict__ X, int ldx, int koff,
    const float* __restrict__ W1, const float* __restrict__ b1,
    float* __restrict__ P, float* __restrict__ Q) {
  constexpr int KT = 16;
  __shared__ float xs[64][KT + 1];
  __shared__ float wt[KT][64];
  __shared__ float wb[KT][64];
  const int tid = threadIdx.x;
  const int row0 = blockIdx.x * 64;
  const int cb0 = blockIdx.y * 64;
  const int cg = tid & 15, rg = tid >> 4;
  const int c0 = cg * 4, r0 = rg * 4;
  float p[4][4] = {}, q[4][4] = {};
  for (int k0 = 0; k0 < K; k0 += KT) {
    const int kt = (K - k0 < KT) ? (K - k0) : KT;
    for (int idx = tid; idx < 64 * KT; idx += 256) {
      int k = idx & (KT - 1), r = idx >> 4;
      if (k < kt) {
        int rr = row0 + r; if (rr >= NNODES) rr = NNODES - 1;
        xs[r][k] = X[(size_t)rr * ldx + koff + k0 + k];
      }
    }
    for (int idx = tid; idx < KT * 64; idx += 256) {
      int k = idx >> 6, c = idx & 63;
      if (k < kt) {
        wt[k][c] = W1[(size_t)(k0 + k) * D + cb0 + c];
        wb[k][c] = W1[(size_t)(K + k0 + k) * D + cb0 + c];
      }
    }
    __syncthreads();
    for (int kk = 0; kk < kt; ++kk) {
      float xv[4];
#pragma unroll
      for (int i = 0; i < 4; ++i) xv[i] = xs[r0 + i][kk];
      const float4 wtv = *(const float4*)&wt[kk][c0];
      const float4 wbv = *(const float4*)&wb[kk][c0];
      float dv[4] = {wtv.x - wbv.x, wtv.y - wbv.y, wtv.z - wbv.z, wtv.w - wbv.w};
      float bv[4] = {wbv.x, wbv.y, wbv.z, wbv.w};
#pragma unroll
      for (int i = 0; i < 4; ++i) {
#pragma unroll
        for (int j = 0; j < 4; ++j) {
          p[i][j] = fmaf(xv[i], dv[j], p[i][j]);
          q[i][j] = fmaf(xv[i], bv[j], q[i][j]);
        }
      }
    }
    __syncthreads();
  }
  float b1v[4];
#pragma unroll
  for (int j = 0; j < 4; ++j) b1v[j] = b1[cb0 + c0 + j];
#pragma unroll
  for (int i = 0; i < 4; ++i) {
    int rr = row0 + r0 + i;
    if (rr < NNODES) {
#pragma unroll
      for (int j = 0; j < 4; ++j) {
        P[(size_t)rr * D + cb0 + c0 + j] = p[i][j] + b1v[j];
        Q[(size_t)rr * D + cb0 + c0 + j] = q[i][j];
      }
    }
  }
}

// Per-edge: t1 = relu(P[dst]+Q[src]); out = t1 @ W2 + b2; atomicMax into agg[dst].
template <int D>
__global__ __launch_bounds__(256) void edge_kernel(
    const int* __restrict__ eidx,
    const float* __restrict__ P, const float* __restrict__ Q,
    const float* __restrict__ W2, const float* __restrict__ b2,
    unsigned* __restrict__ agg) {
  constexpr int BE = (D == 256) ? 32 : 64;  // edges per block
  constexpr int TE = (D == 64) ? 4 : ((D == 128) ? 8 : 4);
  constexpr int TC = (D == 64) ? 4 : ((D == 128) ? 4 : 8);
  constexpr int CG = D / TC;
  constexpr int LPE = 256 / BE;  // lanes cooperating on one edge in phase A
  static_assert((BE / TE) * CG == 256, "thread mapping");
  __shared__ float t1T[D][BE + 1];
  __shared__ float w2s[8][D];
  __shared__ int sSrc[BE], sDst[BE];
  const int tid = threadIdx.x;
  const int ebase = blockIdx.x * BE;
  if (tid < BE) {
    sSrc[tid] = eidx[ebase + tid];
    sDst[tid] = eidx[NEDGES + ebase + tid];
  }
  __syncthreads();
  // Phase A: build t1T[c][e] = relu(P[dst][c] + Q[src][c])  (b1 folded into P)
  {
    const int e = tid / LPE, qd = tid % LPE;
    const float* Pr = P + (size_t)sDst[e] * D;
    const float* Qr = Q + (size_t)sSrc[e] * D;
#pragma unroll
    for (int j = 0; j < D / (4 * LPE); ++j) {
      int c = j * (4 * LPE) + qd * 4;
      float4 pv = *(const float4*)(Pr + c);
      float4 qv = *(const float4*)(Qr + c);
      t1T[c + 0][e] = fmaxf(pv.x + qv.x, 0.0f);
      t1T[c + 1][e] = fmaxf(pv.y + qv.y, 0.0f);
      t1T[c + 2][e] = fmaxf(pv.z + qv.z, 0.0f);
      t1T[c + 3][e] = fmaxf(pv.w + qv.w, 0.0f);
    }
  }
  const int cg = tid % CG, eg = tid / CG;
  const int c0 = cg * TC, e0 = eg * TE;
  float acc[TE][TC] = {};
  __syncthreads();
  for (int k0 = 0; k0 < D; k0 += 8) {
    for (int idx = tid; idx < 2 * D; idx += 256) {
      int k = idx / (D / 4), cq = idx % (D / 4);
      *(float4*)&w2s[k][cq * 4] = *(const float4*)&W2[(size_t)(k0 + k) * D + cq * 4];
    }
    __syncthreads();
#pragma unroll
    for (int kk = 0; kk < 8; ++kk) {
      float tv[TE], wv[TC];
#pragma unroll
      for (int i = 0; i < TE; ++i) tv[i] = t1T[k0 + kk][e0 + i];
#pragma unroll
      for (int j = 0; j < TC; j += 4) *(float4*)&wv[j] = *(const float4*)&w2s[kk][c0 + j];
#pragma unroll
      for (int i = 0; i < TE; ++i) {
#pragma unroll
        for (int j = 0; j < TC; ++j) acc[i][j] = fmaf(tv[i], wv[j], acc[i][j]);
      }
    }
    __syncthreads();
  }
  float bb[TC];
#pragma unroll
  for (int j = 0; j < TC; ++j) bb[j] = b2[c0 + j];
#pragma unroll
  for (int i = 0; i < TE; ++i) {
    const size_t base = (size_t)sDst[e0 + i] * D + c0;
#pragma unroll
    for (int j = 0; j < TC; ++j) {
      atomicMax(&agg[base + j], enc_f32(acc[i][j] + bb[j]));
    }
  }
}

// MLP GEMM: Y = act(X @ W + b). Tile 128 rows x 64 cols.
template <int K, int D, bool RELU>
__global__ __launch_bounds__(256) void mlp_kernel(
    const float* __restrict__ X, int ldx,
    const float* __restrict__ W, const float* __restrict__ b,
    float* __restrict__ Y) {
  constexpr int KT = 16;
  __shared__ float xs[128][KT + 1];
  __shared__ float wS[KT][64];
  const int tid = threadIdx.x;
  const int row0 = blockIdx.x * 128;
  const int cb0 = blockIdx.y * 64;
  const int cg = tid & 15, rg = tid >> 4;
  const int c0 = cg * 4, r0 = rg * 8;
  float acc[8][4] = {};
  for (int k0 = 0; k0 < K; k0 += KT) {
    for (int idx = tid; idx < 128 * KT; idx += 256) {
      int k = idx & 15, r = idx >> 4;
      int rr = row0 + r; if (rr >= NNODES) rr = NNODES - 1;
      xs[r][k] = X[(size_t)rr * ldx + k0 + k];
    }
    for (int idx = tid; idx < KT * 64; idx += 256) {
      int k = idx >> 6, c = idx & 63;
      wS[k][c] = W[(size_t)(k0 + k) * D + cb0 + c];
    }
    __syncthreads();
#pragma unroll
    for (int kk = 0; kk < KT; ++kk) {
      float xv[8];
#pragma unroll
      for (int i = 0; i < 8; ++i) xv[i] = xs[r0 + i][kk];
      const float4 wv = *(const float4*)&wS[kk][c0];
      float wvv[4] = {wv.x, wv.y, wv.z, wv.w};
#pragma unroll
      for (int i = 0; i < 8; ++i) {
#pragma unroll
        for (int j = 0; j < 4; ++j) acc[i][j] = fmaf(xv[i], wvv[j], acc[i][j]);
      }
    }
    __syncthreads();
  }
  float bv[4];
#pragma unroll
  for (int j = 0; j < 4; ++j) bv[j] = b[cb0 + c0 + j];
#pragma unroll
  for (int i = 0; i < 8; ++i) {
    int rr = row0 + r0 + i;
    if (rr < NNODES) {
#pragma unroll
      for (int j = 0; j < 4; ++j) {
        float v = acc[i][j] + bv[j];
        if (RELU) v = fmaxf(v, 0.0f);
        Y[(size_t)rr * D + cb0 + c0 + j] = v;
      }
    }
  }
}

// Final 256 -> 4 projection.
__global__ __launch_bounds__(256) void final_kernel(
    const float* __restrict__ X, const float* __restrict__ W,
    const float* __restrict__ b, float* __restrict__ out) {
  __shared__ float as[64][65];
  __shared__ float ws3[256][4];
  __shared__ float bs[4];
  const int tid = threadIdx.x;
  const int row0 = blockIdx.x * 64;
  for (int idx = tid; idx < 256 * 4; idx += 256) ws3[idx >> 2][idx & 3] = W[idx];
  if (tid < 4) bs[tid] = b[tid];
  const int r = tid >> 2, c = tid & 3;
  float acc = 0.0f;
  for (int k0 = 0; k0 < 256; k0 += 64) {
    __syncthreads();
    for (int idx = tid; idx < 64 * 64; idx += 256) {
      int r2 = idx >> 6, k = idx & 63;
      int rr = row0 + r2; if (rr >= NNODES) rr = NNODES - 1;
      as[r2][k] = X[(size_t)rr * 256 + k0 + k];
    }
    __syncthreads();
#pragma unroll
    for (int kk = 0; kk < 64; ++kk) acc = fmaf(as[r][kk], ws3[k0 + kk][c], acc);
  }
  int rr = row0 + r;
  if (rr < NNODES) out[(size_t)rr * 4 + c] = acc + bs[c];
}

extern "C" void kernel_launch(void* const* d_in, const int* in_sizes, int n_in,
                              void* d_out, int out_size, void* d_ws, size_t ws_size,
                              hipStream_t stream) {
  const float* x = (const float*)d_in[0];
  const int* eidx = (const int*)d_in[1];   // int32! harness passes integers as int
  // d_in[2] = batch (int32, unused)
  const float* w1a = (const float*)d_in[3];
  const float* b1a = (const float*)d_in[4];
  const float* w1b = (const float*)d_in[5];
  const float* b1b = (const float*)d_in[6];
  const float* w2a = (const float*)d_in[7];
  const float* b2a = (const float*)d_in[8];
  const float* w2b = (const float*)d_in[9];
  const float* b2b = (const float*)d_in[10];
  const float* w3a = (const float*)d_in[11];
  const float* b3a = (const float*)d_in[12];
  const float* w3b = (const float*)d_in[13];
  const float* b3b = (const float*)d_in[14];
  const float* wm1 = (const float*)d_in[15];
  const float* bm1 = (const float*)d_in[16];
  const float* wm2 = (const float*)d_in[17];
  const float* bm2 = (const float*)d_in[18];
  const float* wm3 = (const float*)d_in[19];
  const float* bm3 = (const float*)d_in[20];
  float* out = (float*)d_out;

  // Workspace layout (floats): hcat[N*448] | P[N*256] | Q[N*256] | agg[N*256]
  // mh1 (N*512) overlays P+Q; mh2 (N*256) overlays agg. Total 145.92 MB.
  float* wsf = (float*)d_ws;
  float* hcat = wsf;
  float* P = wsf + (size_t)NNODES * 448;
  float* Q = P + (size_t)NNODES * 256;
  unsigned* agg = (unsigned*)(Q + (size_t)NNODES * 256);
  float* mh1 = P;
  float* mh2 = (float*)agg;

  const int ROWB64 = (NNODES + 63) / 64;     // 469
  const int ROWB128 = (NNODES + 127) / 128;  // 235

  // ---- EdgeConv 1: C=3 -> 64
  {
    int total = NNODES * 64;
    fill_u32<<<(total + 255) / 256, 256, 0, stream>>>(agg, total, ENC_NEGINF);
    pq_kernel<3, 64><<<dim3(ROWB64, 1), 256, 0, stream>>>(x, 3, 0, w1a, b1a, P, Q);
    edge_kernel<64><<<NEDGES / 64, 256, 0, stream>>>(eidx, P, Q, w1b, b1b, agg);
    decode_kernel<<<(total + 255) / 256, 256, 0, stream>>>(agg, hcat + 0, 6, total);
  }
  // ---- EdgeConv 2: C=64 -> 128  (input: hcat cols 0..63)
  {
    int total = NNODES * 128;
    fill_u32<<<(total + 255) / 256, 256, 0, stream>>>(agg, total, ENC_NEGINF);
    pq_kernel<64, 128><<<dim3(ROWB64, 2), 256, 0, stream>>>(hcat, 448, 0, w2a, b2a, P, Q);
    edge_kernel<128><<<NEDGES / 64, 256, 0, stream>>>(eidx, P, Q, w2b, b2b, agg);
    decode_kernel<<<(total + 255) / 256, 256, 0, stream>>>(agg, hcat + 64, 7, total);
  }
  // ---- EdgeConv 3: C=128 -> 256  (input: hcat cols 64..191)
  {
    int total = NNODES * 256;
    fill_u32<<<(total + 255) / 256, 256, 0, stream>>>(agg, total, ENC_NEGINF);
    pq_kernel<128, 256><<<dim3(ROWB64, 4), 256, 0, stream>>>(hcat, 448, 64, w3a, b3a, P, Q);
    edge_kernel<256><<<NEDGES / 32, 256, 0, stream>>>(eidx, P, Q, w3b, b3b, agg);
    decode_kernel<<<(total + 255) / 256, 256, 0, stream>>>(agg, hcat + 192, 8, total);
  }
  // ---- MLP head
  mlp_kernel<448, 512, true><<<dim3(ROWB128, 8), 256, 0, stream>>>(hcat, 448, wm1, bm1, mh1);
  mlp_kernel<512, 256, true><<<dim3(ROWB128, 4), 256, 0, stream>>>(mh1, 512, wm2, bm2, mh2);
  final_kernel<<<ROWB64, 256, 0, stream>>>(mh2, wm3, bm3, out);
}

// Round 3
// 2030.149 us; speedup vs baseline: 2.3005x; 2.3005x over previous
//
#include <hip/hip_runtime.h>
#include <cstdint>
#include <cstddef>
#include <math.h>

#define NNODES 30000
#define NEDGES 480000

constexpr unsigned ENC_NEGINF = 0x007FFFFFu;  // encode(-inf)

__device__ __forceinline__ unsigned enc_f32(float f) {
  unsigned u = __float_as_uint(f);
  return (u & 0x80000000u) ? ~u : (u | 0x80000000u);
}
__device__ __forceinline__ float dec_f32(unsigned e) {
  unsigned u = (e & 0x80000000u) ? (e ^ 0x80000000u) : ~e;
  return __uint_as_float(u);
}

__global__ void fill_u32(unsigned* __restrict__ p, int n, unsigned v) {
  int i = blockIdx.x * 256 + threadIdx.x;
  if (i < n) p[i] = v;
}

// ---- CSR build: histogram -> exclusive scan -> scatter (sorted by dst) ----
__global__ void hist_kernel(const int* __restrict__ eidx, int* __restrict__ deg) {
  int e = blockIdx.x * 256 + threadIdx.x;
  if (e < NEDGES) atomicAdd(&deg[eidx[NEDGES + e]], 1);
}

__global__ __launch_bounds__(1024) void scan_kernel(const int* __restrict__ deg,
                                                    int* __restrict__ cur) {
  __shared__ int part[1024];
  const int tid = threadIdx.x;
  constexpr int PER = 30;  // 1024*30 = 30720 >= 30000
  int loc[PER];
  int s = 0;
  const int base = tid * PER;
#pragma unroll
  for (int i = 0; i < PER; ++i) {
    int idx = base + i;
    int v = (idx < NNODES) ? deg[idx] : 0;
    loc[i] = s;
    s += v;
  }
  part[tid] = s;
  __syncthreads();
  for (int d = 1; d < 1024; d <<= 1) {
    int t = (tid >= d) ? part[tid - d] : 0;
    __syncthreads();
    part[tid] += t;
    __syncthreads();
  }
  const int excl = part[tid] - s;
#pragma unroll
  for (int i = 0; i < PER; ++i) {
    int idx = base + i;
    if (idx < NNODES) cur[idx] = excl + loc[i];
  }
}

// Pack (dst<<16)|src — both < 30000 < 65536.
__global__ void scatter_kernel(const int* __restrict__ eidx, int* __restrict__ cur,
                               unsigned* __restrict__ sedge) {
  int e = blockIdx.x * 256 + threadIdx.x;
  if (e < NEDGES) {
    int s = eidx[e], d = eidx[NEDGES + e];
    int pos = atomicAdd(&cur[d], 1);
    sedge[pos] = ((unsigned)d << 16) | (unsigned)s;
  }
}

// Decode encoded max-agg into hcat slice (hc already offset by column).
__global__ void decode_kernel(const unsigned* __restrict__ agg, float* __restrict__ hc,
                              int shift, int total) {
  int i = blockIdx.x * 256 + threadIdx.x;
  if (i < total) {
    unsigned e = agg[i];
    float v = (e == ENC_NEGINF) ? 0.0f : dec_f32(e);
    int r = i >> shift;
    int c = i & ((1 << shift) - 1);
    hc[(size_t)r * 448 + c] = v;
  }
}

// P[n] = x[n] @ (W1_top - W1_bot) + b1 ; Q[n] = x[n] @ W1_bot
template <int K, int D>
__global__ __launch_bounds__(256) void pq_kernel(
    const float* __restrict__ X, int ldx, int koff,
    const float* __restrict__ W1, const float* __restrict__ b1,
    float* __restrict__ P, float* __restrict__ Q) {
  constexpr int KT = 16;
  __shared__ float xs[64][KT + 1];
  __shared__ float wt[KT][64];
  __shared__ float wb[KT][64];
  const int tid = threadIdx.x;
  const int row0 = blockIdx.x * 64;
  const int cb0 = blockIdx.y * 64;
  const int cg = tid & 15, rg = tid >> 4;
  const int c0 = cg * 4, r0 = rg * 4;
  float p[4][4] = {}, q[4][4] = {};
  for (int k0 = 0; k0 < K; k0 += KT) {
    const int kt = (K - k0 < KT) ? (K - k0) : KT;
    for (int idx = tid; idx < 64 * KT; idx += 256) {
      int k = idx & (KT - 1), r = idx >> 4;
      if (k < kt) {
        int rr = row0 + r; if (rr >= NNODES) rr = NNODES - 1;
        xs[r][k] = X[(size_t)rr * ldx + koff + k0 + k];
      }
    }
    for (int idx = tid; idx < KT * 64; idx += 256) {
      int k = idx >> 6, c = idx & 63;
      if (k < kt) {
        wt[k][c] = W1[(size_t)(k0 + k) * D + cb0 + c];
        wb[k][c] = W1[(size_t)(K + k0 + k) * D + cb0 + c];
      }
    }
    __syncthreads();
    for (int kk = 0; kk < kt; ++kk) {
      float xv[4];
#pragma unroll
      for (int i = 0; i < 4; ++i) xv[i] = xs[r0 + i][kk];
      const float4 wtv = *(const float4*)&wt[kk][c0];
      const float4 wbv = *(const float4*)&wb[kk][c0];
      float dv[4] = {wtv.x - wbv.x, wtv.y - wbv.y, wtv.z - wbv.z, wtv.w - wbv.w};
      float bv[4] = {wbv.x, wbv.y, wbv.z, wbv.w};
#pragma unroll
      for (int i = 0; i < 4; ++i) {
#pragma unroll
        for (int j = 0; j < 4; ++j) {
          p[i][j] = fmaf(xv[i], dv[j], p[i][j]);
          q[i][j] = fmaf(xv[i], bv[j], q[i][j]);
        }
      }
    }
    __syncthreads();
  }
  float b1v[4];
#pragma unroll
  for (int j = 0; j < 4; ++j) b1v[j] = b1[cb0 + c0 + j];
#pragma unroll
  for (int i = 0; i < 4; ++i) {
    int rr = row0 + r0 + i;
    if (rr < NNODES) {
#pragma unroll
      for (int j = 0; j < 4; ++j) {
        P[(size_t)rr * D + cb0 + c0 + j] = p[i][j] + b1v[j];
        Q[(size_t)rr * D + cb0 + c0 + j] = q[i][j];
      }
    }
  }
}

// Per-edge (dst-sorted): t1 = relu(P[dst]+Q[src]); y = t1 @ W2 + b2;
// in-tile per-column segmented max over sorted dst, then few atomicMax.
template <int D>
__global__ __launch_bounds__(256) void edge_kernel(
    const unsigned* __restrict__ sedge,
    const float* __restrict__ P, const float* __restrict__ Q,
    const float* __restrict__ W2, const float* __restrict__ b2,
    unsigned* __restrict__ agg) {
  constexpr int BE = (D == 256) ? 32 : 64;  // edges per block
  constexpr int TE = (D == 64) ? 4 : ((D == 128) ? 8 : 4);
  constexpr int TC = (D == 64) ? 4 : ((D == 128) ? 4 : 8);
  constexpr int CG = D / TC;
  constexpr int LPE = 256 / BE;   // lanes per edge in phase A
  constexpr int SL = BE * D / 256;  // edges per scan slice in phase C
  static_assert((BE / TE) * CG == 256, "thread mapping");
  __shared__ float sbuf[D * (BE + 1)];  // t1T in phases A/B, accT in phase C
  __shared__ float w2s[8][D];
  __shared__ int sSrc[BE], sDst[BE];
#define T1T(c, e) sbuf[(c) * (BE + 1) + (e)]
  const int tid = threadIdx.x;
  const int ebase = blockIdx.x * BE;
  if (tid < BE) {
    unsigned pk = sedge[ebase + tid];
    sSrc[tid] = (int)(pk & 0xFFFFu);
    sDst[tid] = (int)(pk >> 16);
  }
  __syncthreads();
  // Phase A: t1T[c][e] = relu(P[dst][c] + Q[src][c])  (b1 folded into P)
  {
    const int e = tid / LPE, qd = tid % LPE;
    const float* Pr = P + (size_t)sDst[e] * D;
    const float* Qr = Q + (size_t)sSrc[e] * D;
#pragma unroll
    for (int j = 0; j < D / (4 * LPE); ++j) {
      int c = j * (4 * LPE) + qd * 4;
      float4 pv = *(const float4*)(Pr + c);
      float4 qv = *(const float4*)(Qr + c);
      T1T(c + 0, e) = fmaxf(pv.x + qv.x, 0.0f);
      T1T(c + 1, e) = fmaxf(pv.y + qv.y, 0.0f);
      T1T(c + 2, e) = fmaxf(pv.z + qv.z, 0.0f);
      T1T(c + 3, e) = fmaxf(pv.w + qv.w, 0.0f);
    }
  }
  const int cg = tid % CG, eg = tid / CG;
  const int c0 = cg * TC, e0 = eg * TE;
  float acc[TE][TC] = {};
  __syncthreads();
  // Phase B: acc = t1 @ W2
  for (int k0 = 0; k0 < D; k0 += 8) {
    for (int idx = tid; idx < 2 * D; idx += 256) {
      int k = idx / (D / 4), cq = idx % (D / 4);
      *(float4*)&w2s[k][cq * 4] = *(const float4*)&W2[(size_t)(k0 + k) * D + cq * 4];
    }
    __syncthreads();
#pragma unroll
    for (int kk = 0; kk < 8; ++kk) {
      float tv[TE], wv[TC];
#pragma unroll
      for (int i = 0; i < TE; ++i) tv[i] = T1T(k0 + kk, e0 + i);
#pragma unroll
      for (int j = 0; j < TC; j += 4) *(float4*)&wv[j] = *(const float4*)&w2s[kk][c0 + j];
#pragma unroll
      for (int i = 0; i < TE; ++i) {
#pragma unroll
        for (int j = 0; j < TC; ++j) acc[i][j] = fmaf(tv[i], wv[j], acc[i][j]);
      }
    }
    __syncthreads();
  }
  // Phase C: acc (+bias) -> LDS (reuse sbuf), then per-column segmented max.
  float bb[TC];
#pragma unroll
  for (int j = 0; j < TC; ++j) bb[j] = b2[c0 + j];
#pragma unroll
  for (int i = 0; i < TE; ++i) {
#pragma unroll
    for (int j = 0; j < TC; ++j) T1T(c0 + j, e0 + i) = acc[i][j] + bb[j];
  }
  __syncthreads();
  {
    const int c = tid % D;
    const int g = tid / D;
    const int es = g * SL;
    float run = -INFINITY;
    int pd = sDst[es];
    for (int e = es; e < es + SL; ++e) {
      int d = sDst[e];
      if (d != pd) {
        atomicMax(&agg[(size_t)pd * D + c], enc_f32(run));
        run = -INFINITY;
        pd = d;
      }
      run = fmaxf(run, T1T(c, e));
    }
    atomicMax(&agg[(size_t)pd * D + c], enc_f32(run));
  }
#undef T1T
}

// MLP GEMM: Y = act(X @ W + b). Tile 128 rows x 64 cols.
template <int K, int D, bool RELU>
__global__ __launch_bounds__(256) void mlp_kernel(
    const float* __restrict__ X, int ldx,
    const float* __restrict__ W, const float* __restrict__ b,
    float* __restrict__ Y) {
  constexpr int KT = 16;
  __shared__ float xs[128][KT + 1];
  __shared__ float wS[KT][64];
  const int tid = threadIdx.x;
  const int row0 = blockIdx.x * 128;
  const int cb0 = blockIdx.y * 64;
  const int cg = tid & 15, rg = tid >> 4;
  const int c0 = cg * 4, r0 = rg * 8;
  float acc[8][4] = {};
  for (int k0 = 0; k0 < K; k0 += KT) {
    for (int idx = tid; idx < 128 * KT; idx += 256) {
      int k = idx & 15, r = idx >> 4;
      int rr = row0 + r; if (rr >= NNODES) rr = NNODES - 1;
      xs[r][k] = X[(size_t)rr * ldx + k0 + k];
    }
    for (int idx = tid; idx < KT * 64; idx += 256) {
      int k = idx >> 6, c = idx & 63;
      wS[k][c] = W[(size_t)(k0 + k) * D + cb0 + c];
    }
    __syncthreads();
#pragma unroll
    for (int kk = 0; kk < KT; ++kk) {
      float xv[8];
#pragma unroll
      for (int i = 0; i < 8; ++i) xv[i] = xs[r0 + i][kk];
      const float4 wv = *(const float4*)&wS[kk][c0];
      float wvv[4] = {wv.x, wv.y, wv.z, wv.w};
#pragma unroll
      for (int i = 0; i < 8; ++i) {
#pragma unroll
        for (int j = 0; j < 4; ++j) acc[i][j] = fmaf(xv[i], wvv[j], acc[i][j]);
      }
    }
    __syncthreads();
  }
  float bv[4];
#pragma unroll
  for (int j = 0; j < 4; ++j) bv[j] = b[cb0 + c0 + j];
#pragma unroll
  for (int i = 0; i < 8; ++i) {
    int rr = row0 + r0 + i;
    if (rr < NNODES) {
#pragma unroll
      for (int j = 0; j < 4; ++j) {
        float v = acc[i][j] + bv[j];
        if (RELU) v = fmaxf(v, 0.0f);
        Y[(size_t)rr * D + cb0 + c0 + j] = v;
      }
    }
  }
}

// Final 256 -> 4 projection.
__global__ __launch_bounds__(256) void final_kernel(
    const float* __restrict__ X, const float* __restrict__ W,
    const float* __restrict__ b, float* __restrict__ out) {
  __shared__ float as[64][65];
  __shared__ float ws3[256][4];
  __shared__ float bs[4];
  const int tid = threadIdx.x;
  const int row0 = blockIdx.x * 64;
  for (int idx = tid; idx < 256 * 4; idx += 256) ws3[idx >> 2][idx & 3] = W[idx];
  if (tid < 4) bs[tid] = b[tid];
  const int r = tid >> 2, c = tid & 3;
  float acc = 0.0f;
  for (int k0 = 0; k0 < 256; k0 += 64) {
    __syncthreads();
    for (int idx = tid; idx < 64 * 64; idx += 256) {
      int r2 = idx >> 6, k = idx & 63;
      int rr = row0 + r2; if (rr >= NNODES) rr = NNODES - 1;
      as[r2][k] = X[(size_t)rr * 256 + k0 + k];
    }
    __syncthreads();
#pragma unroll
    for (int kk = 0; kk < 64; ++kk) acc = fmaf(as[r][kk], ws3[k0 + kk][c], acc);
  }
  int rr = row0 + r;
  if (rr < NNODES) out[(size_t)rr * 4 + c] = acc + bs[c];
}

extern "C" void kernel_launch(void* const* d_in, const int* in_sizes, int n_in,
                              void* d_out, int out_size, void* d_ws, size_t ws_size,
                              hipStream_t stream) {
  const float* x = (const float*)d_in[0];
  const int* eidx = (const int*)d_in[1];  // int32
  const float* w1a = (const float*)d_in[3];
  const float* b1a = (const float*)d_in[4];
  const float* w1b = (const float*)d_in[5];
  const float* b1b = (const float*)d_in[6];
  const float* w2a = (const float*)d_in[7];
  const float* b2a = (const float*)d_in[8];
  const float* w2b = (const float*)d_in[9];
  const float* b2b = (const float*)d_in[10];
  const float* w3a = (const float*)d_in[11];
  const float* b3a = (const float*)d_in[12];
  const float* w3b = (const float*)d_in[13];
  const float* b3b = (const float*)d_in[14];
  const float* wm1 = (const float*)d_in[15];
  const float* bm1 = (const float*)d_in[16];
  const float* wm2 = (const float*)d_in[17];
  const float* bm2 = (const float*)d_in[18];
  const float* wm3 = (const float*)d_in[19];
  const float* bm3 = (const float*)d_in[20];
  float* out = (float*)d_out;

  // Workspace (floats): hcat[N*448] | P[N*256] | Q[N*256] | agg[N*256] | sedge[E]
  // deg/cur overlay agg (used only during CSR build, before agg init).
  // mh1 overlays P+Q; mh2 overlays agg. Total ~147.8 MB.
  float* wsf = (float*)d_ws;
  float* hcat = wsf;
  float* P = wsf + (size_t)NNODES * 448;
  float* Q = P + (size_t)NNODES * 256;
  unsigned* agg = (unsigned*)(Q + (size_t)NNODES * 256);
  unsigned* sedge = agg + (size_t)NNODES * 256;
  int* deg = (int*)agg;
  int* cur = deg + NNODES;
  float* mh1 = P;
  float* mh2 = (float*)agg;

  const int ROWB64 = (NNODES + 63) / 64;     // 469
  const int ROWB128 = (NNODES + 127) / 128;  // 235
  const int EB = (NEDGES + 255) / 256;

  // ---- Build dst-sorted edge list (CSR order), reused by all 3 layers
  fill_u32<<<(NNODES + 255) / 256, 256, 0, stream>>>((unsigned*)deg, NNODES, 0u);
  hist_kernel<<<EB, 256, 0, stream>>>(eidx, deg);
  scan_kernel<<<1, 1024, 0, stream>>>(deg, cur);
  scatter_kernel<<<EB, 256, 0, stream>>>(eidx, cur, sedge);

  // ---- EdgeConv 1: C=3 -> 64
  {
    int total = NNODES * 64;
    fill_u32<<<(total + 255) / 256, 256, 0, stream>>>(agg, total, ENC_NEGINF);
    pq_kernel<3, 64><<<dim3(ROWB64, 1), 256, 0, stream>>>(x, 3, 0, w1a, b1a, P, Q);
    edge_kernel<64><<<NEDGES / 64, 256, 0, stream>>>(sedge, P, Q, w1b, b1b, agg);
    decode_kernel<<<(total + 255) / 256, 256, 0, stream>>>(agg, hcat + 0, 6, total);
  }
  // ---- EdgeConv 2: C=64 -> 128
  {
    int total = NNODES * 128;
    fill_u32<<<(total + 255) / 256, 256, 0, stream>>>(agg, total, ENC_NEGINF);
    pq_kernel<64, 128><<<dim3(ROWB64, 2), 256, 0, stream>>>(hcat, 448, 0, w2a, b2a, P, Q);
    edge_kernel<128><<<NEDGES / 64, 256, 0, stream>>>(sedge, P, Q, w2b, b2b, agg);
    decode_kernel<<<(total + 255) / 256, 256, 0, stream>>>(agg, hcat + 64, 7, total);
  }
  // ---- EdgeConv 3: C=128 -> 256
  {
    int total = NNODES * 256;
    fill_u32<<<(total + 255) / 256, 256, 0, stream>>>(agg, total, ENC_NEGINF);
    pq_kernel<128, 256><<<dim3(ROWB64, 4), 256, 0, stream>>>(hcat, 448, 64, w3a, b3a, P, Q);
    edge_kernel<256><<<NEDGES / 32, 256, 0, stream>>>(sedge, P, Q, w3b, b3b, agg);
    decode_kernel<<<(total + 255) / 256, 256, 0, stream>>>(agg, hcat + 192, 8, total);
  }
  // ---- MLP head
  mlp_kernel<448, 512, true><<<dim3(ROWB128, 8), 256, 0, stream>>>(hcat, 448, wm1, bm1, mh1);
  mlp_kernel<512, 256, true><<<dim3(ROWB128, 4), 256, 0, stream>>>(mh1, 512, wm2, bm2, mh2);
  final_kernel<<<ROWB64, 256, 0, stream>>>(mh2, wm3, bm3, out);
}

// Round 4
// 1087.181 us; speedup vs baseline: 4.2958x; 1.8674x over previous
//
#include <hip/hip_runtime.h>
#include <cstdint>
#include <cstddef>
#include <math.h>

#define NNODES 30000
#define NEDGES 480000

typedef _Float16 f16x8 __attribute__((ext_vector_type(8)));
typedef float f32x4 __attribute__((ext_vector_type(4)));

constexpr unsigned ENC_NEGINF = 0x007FFFFFu;  // encode(-inf)

__device__ __forceinline__ unsigned enc_f32(float f) {
  unsigned u = __float_as_uint(f);
  return (u & 0x80000000u) ? ~u : (u | 0x80000000u);
}
__device__ __forceinline__ float dec_f32(unsigned e) {
  unsigned u = (e & 0x80000000u) ? (e ^ 0x80000000u) : ~e;
  return __uint_as_float(u);
}

__global__ void fill_u32(unsigned* __restrict__ p, int n, unsigned v) {
  int i = blockIdx.x * 256 + threadIdx.x;
  if (i < n) p[i] = v;
}

// ---- CSR build: histogram -> exclusive scan -> scatter (sorted by dst) ----
__global__ void hist_kernel(const int* __restrict__ eidx, int* __restrict__ deg) {
  int e = blockIdx.x * 256 + threadIdx.x;
  if (e < NEDGES) atomicAdd(&deg[eidx[NEDGES + e]], 1);
}

__global__ __launch_bounds__(1024) void scan_kernel(const int* __restrict__ deg,
                                                    int* __restrict__ cur) {
  __shared__ int part[1024];
  const int tid = threadIdx.x;
  constexpr int PER = 30;  // 1024*30 = 30720 >= 30000
  int loc[PER];
  int s = 0;
  const int base = tid * PER;
#pragma unroll
  for (int i = 0; i < PER; ++i) {
    int idx = base + i;
    int v = (idx < NNODES) ? deg[idx] : 0;
    loc[i] = s;
    s += v;
  }
  part[tid] = s;
  __syncthreads();
  for (int d = 1; d < 1024; d <<= 1) {
    int t = (tid >= d) ? part[tid - d] : 0;
    __syncthreads();
    part[tid] += t;
    __syncthreads();
  }
  const int excl = part[tid] - s;
#pragma unroll
  for (int i = 0; i < PER; ++i) {
    int idx = base + i;
    if (idx < NNODES) cur[idx] = excl + loc[i];
  }
}

// Pack (dst<<16)|src — both < 30000 < 65536.
__global__ void scatter_kernel(const int* __restrict__ eidx, int* __restrict__ cur,
                               unsigned* __restrict__ sedge) {
  int e = blockIdx.x * 256 + threadIdx.x;
  if (e < NEDGES) {
    int s = eidx[e], d = eidx[NEDGES + e];
    int pos = atomicAdd(&cur[d], 1);
    sedge[pos] = ((unsigned)d << 16) | (unsigned)s;
  }
}

// Transposed f16 weight: BT[n*Dd + k] = (f16) W[k*Dd + n]
__global__ void cvt_wT(const float* __restrict__ W, _Float16* __restrict__ BT, int Dd) {
  int idx = blockIdx.x * 256 + threadIdx.x;
  if (idx < Dd * Dd) {
    int k = idx / Dd, n = idx % Dd;          // coalesced read of W[k][n]
    BT[n * Dd + k] = (_Float16)W[idx];
  }
}

// Decode encoded max-agg into hcat slice (hc already offset by column).
__global__ void decode_kernel(const unsigned* __restrict__ agg, float* __restrict__ hc,
                              int shift, int total) {
  int i = blockIdx.x * 256 + threadIdx.x;
  if (i < total) {
    unsigned e = agg[i];
    float v = (e == ENC_NEGINF) ? 0.0f : dec_f32(e);
    int r = i >> shift;
    int c = i & ((1 << shift) - 1);
    hc[(size_t)r * 448 + c] = v;
  }
}

// P[n] = x[n] @ (W1_top - W1_bot) + b1 ; Q[n] = x[n] @ W1_bot
template <int K, int D>
__global__ __launch_bounds__(256) void pq_kernel(
    const float* __restrict__ X, int ldx, int koff,
    const float* __restrict__ W1, const float* __restrict__ b1,
    float* __restrict__ P, float* __restrict__ Q) {
  constexpr int KT = 16;
  __shared__ float xs[64][KT + 1];
  __shared__ float wt[KT][64];
  __shared__ float wb[KT][64];
  const int tid = threadIdx.x;
  const int row0 = blockIdx.x * 64;
  const int cb0 = blockIdx.y * 64;
  const int cg = tid & 15, rg = tid >> 4;
  const int c0 = cg * 4, r0 = rg * 4;
  float p[4][4] = {}, q[4][4] = {};
  for (int k0 = 0; k0 < K; k0 += KT) {
    const int kt = (K - k0 < KT) ? (K - k0) : KT;
    for (int idx = tid; idx < 64 * KT; idx += 256) {
      int k = idx & (KT - 1), r = idx >> 4;
      if (k < kt) {
        int rr = row0 + r; if (rr >= NNODES) rr = NNODES - 1;
        xs[r][k] = X[(size_t)rr * ldx + koff + k0 + k];
      }
    }
    for (int idx = tid; idx < KT * 64; idx += 256) {
      int k = idx >> 6, c = idx & 63;
      if (k < kt) {
        wt[k][c] = W1[(size_t)(k0 + k) * D + cb0 + c];
        wb[k][c] = W1[(size_t)(K + k0 + k) * D + cb0 + c];
      }
    }
    __syncthreads();
    for (int kk = 0; kk < kt; ++kk) {
      float xv[4];
#pragma unroll
      for (int i = 0; i < 4; ++i) xv[i] = xs[r0 + i][kk];
      const float4 wtv = *(const float4*)&wt[kk][c0];
      const float4 wbv = *(const float4*)&wb[kk][c0];
      float dv[4] = {wtv.x - wbv.x, wtv.y - wbv.y, wtv.z - wbv.z, wtv.w - wbv.w};
      float bv[4] = {wbv.x, wbv.y, wbv.z, wbv.w};
#pragma unroll
      for (int i = 0; i < 4; ++i) {
#pragma unroll
        for (int j = 0; j < 4; ++j) {
          p[i][j] = fmaf(xv[i], dv[j], p[i][j]);
          q[i][j] = fmaf(xv[i], bv[j], q[i][j]);
        }
      }
    }
    __syncthreads();
  }
  float b1v[4];
#pragma unroll
  for (int j = 0; j < 4; ++j) b1v[j] = b1[cb0 + c0 + j];
#pragma unroll
  for (int i = 0; i < 4; ++i) {
    int rr = row0 + r0 + i;
    if (rr < NNODES) {
#pragma unroll
      for (int j = 0; j < 4; ++j) {
        P[(size_t)rr * D + cb0 + c0 + j] = p[i][j] + b1v[j];
        Q[(size_t)rr * D + cb0 + c0 + j] = q[i][j];
      }
    }
  }
}

// MFMA edge kernel (dst-sorted edges): t1 = relu(P[dst]+Q[src]) -> f16 LDS;
// y = t1 @ W2 via v_mfma_f32_16x16x32_f16 (fp32 acc); +b2; in-block segmented
// max over sorted dst; few atomicMax to agg.
template <int D>
__global__ __launch_bounds__(256) void edge_mfma(
    const unsigned* __restrict__ sedge,
    const float* __restrict__ P, const float* __restrict__ Q,
    const _Float16* __restrict__ BT,  // [n][k] f16 transposed W2
    const float* __restrict__ b2,
    unsigned* __restrict__ agg) {
  constexpr int BE = 64;                 // edges per block
  constexpr int MT = 4;                  // M(edge)-tiles of 16
  constexpr int NT = D / 64;             // N-tiles per wave
  constexpr int SA = D + 8;              // A stride in halves (+8 kills bank conflicts)
  constexpr bool STAGED = (D == 256);
  constexpr int SB = STAGED ? 40 : (D + 8);
  constexpr int KS = 32;                 // K per MFMA step
  constexpr int NSTEP = D / KS;
  constexpr int ABYTES = BE * SA * 2;
  constexpr int BROWS = STAGED ? 256 : D;
  constexpr int BBYTES = BROWS * SB * 2;
  __shared__ __align__(16) char smem[ABYTES + BBYTES];
  __shared__ int sSrc[BE], sDst[BE];
  _Float16* Abuf = (_Float16*)smem;
  _Float16* Bbuf = (_Float16*)(smem + ABYTES);
  float* ybuf = (float*)smem;            // overlays A(+B) after GEMM

  const int tid = threadIdx.x;
  const int wave = tid >> 6, lane = tid & 63;
  const int l16 = lane & 15, quad = lane >> 4;
  const int ebase = blockIdx.x * BE;
  if (tid < BE) {
    unsigned pk = sedge[ebase + tid];
    sSrc[tid] = (int)(pk & 0xFFFFu);
    sDst[tid] = (int)(pk >> 16);
  }
  __syncthreads();
  // ---- Phase A: t1 (f16) into Abuf[e][k]
  {
    const int e = tid >> 2, qd = tid & 3;
    const float* Pr = P + (size_t)sDst[e] * D;
    const float* Qr = Q + (size_t)sSrc[e] * D;
#pragma unroll
    for (int t = 0; t < D / 32; ++t) {
      int k = (qd + 4 * t) * 8;
      float4 p0 = *(const float4*)(Pr + k);
      float4 p1 = *(const float4*)(Pr + k + 4);
      float4 q0 = *(const float4*)(Qr + k);
      float4 q1 = *(const float4*)(Qr + k + 4);
      union { _Float16 h[8]; float4 f4; } u;
      u.h[0] = (_Float16)fmaxf(p0.x + q0.x, 0.0f);
      u.h[1] = (_Float16)fmaxf(p0.y + q0.y, 0.0f);
      u.h[2] = (_Float16)fmaxf(p0.z + q0.z, 0.0f);
      u.h[3] = (_Float16)fmaxf(p0.w + q0.w, 0.0f);
      u.h[4] = (_Float16)fmaxf(p1.x + q1.x, 0.0f);
      u.h[5] = (_Float16)fmaxf(p1.y + q1.y, 0.0f);
      u.h[6] = (_Float16)fmaxf(p1.z + q1.z, 0.0f);
      u.h[7] = (_Float16)fmaxf(p1.w + q1.w, 0.0f);
      *(float4*)&Abuf[e * SA + k] = u.f4;
    }
  }
  // ---- Phase B: GEMM
  f32x4 acc[MT][NT] = {};
  auto kstep = [&](int ka, int kb) {
    f16x8 af[MT], bf[NT];
#pragma unroll
    for (int mt = 0; mt < MT; ++mt)
      af[mt] = *(const f16x8*)&Abuf[(mt * 16 + l16) * SA + ka + quad * 8];
#pragma unroll
    for (int nt = 0; nt < NT; ++nt)
      bf[nt] = *(const f16x8*)&Bbuf[(wave * NT * 16 + nt * 16 + l16) * SB + kb + quad * 8];
#pragma unroll
    for (int mt = 0; mt < MT; ++mt)
#pragma unroll
      for (int nt = 0; nt < NT; ++nt)
        acc[mt][nt] = __builtin_amdgcn_mfma_f32_16x16x32_f16(af[mt], bf[nt], acc[mt][nt], 0, 0, 0);
  };
  if (!STAGED) {
    constexpr int CH = D / 8;
    for (int idx = tid; idx < D * CH; idx += 256) {
      int n = idx / CH, cc = idx % CH;
      *(float4*)&Bbuf[n * SB + cc * 8] = *(const float4*)&BT[(size_t)n * D + cc * 8];
    }
    __syncthreads();  // covers Abuf + Bbuf
    for (int ks = 0; ks < NSTEP; ++ks) kstep(ks * KS, ks * KS);
  } else {
    for (int ks = 0; ks < NSTEP; ++ks) {
      __syncthreads();  // prev slice consumed (first iter: Abuf ready)
      for (int i = 0; i < 4; ++i) {
        int idx = i * 256 + tid;
        int n = idx >> 2, cc = idx & 3;
        *(float4*)&Bbuf[n * SB + cc * 8] = *(const float4*)&BT[(size_t)n * 256 + ks * KS + cc * 8];
      }
      __syncthreads();
      kstep(ks * KS, 0);
    }
  }
  // ---- Phase C: +bias, segmented max over sorted dst, atomics
  constexpr int HALVES = STAGED ? 2 : 1;
  constexpr int CPH = D / HALVES;        // cols per half
  constexpr int WPH = 4 / HALVES;        // waves per half
  constexpr int SL = BE * CPH / 256;     // edges per scan slice
  for (int h = 0; h < HALVES; ++h) {
    __syncthreads();
    if (wave / WPH == h) {
#pragma unroll
      for (int mt = 0; mt < MT; ++mt)
#pragma unroll
        for (int nt = 0; nt < NT; ++nt) {
          int ng = wave * NT * 16 + nt * 16 + l16;
          float bias = b2[ng];
          int nl = ng - h * CPH;
#pragma unroll
          for (int r = 0; r < 4; ++r)
            ybuf[nl * (BE + 1) + mt * 16 + quad * 4 + r] = acc[mt][nt][r] + bias;
        }
    }
    __syncthreads();
    {
      const int c = tid % CPH, g = tid / CPH;
      const int es = g * SL;
      float run = -INFINITY;
      int pd = sDst[es];
      for (int e = es; e < es + SL; ++e) {
        int d = sDst[e];
        if (d != pd) {
          atomicMax(&agg[(size_t)pd * D + h * CPH + c], enc_f32(run));
          run = -INFINITY;
          pd = d;
        }
        run = fmaxf(run, ybuf[c * (BE + 1) + e]);
      }
      atomicMax(&agg[(size_t)pd * D + h * CPH + c], enc_f32(run));
    }
  }
}

// MLP GEMM: Y = act(X @ W + b). Tile 128 rows x 64 cols.
template <int K, int D, bool RELU>
__global__ __launch_bounds__(256) void mlp_kernel(
    const float* __restrict__ X, int ldx,
    const float* __restrict__ W, const float* __restrict__ b,
    float* __restrict__ Y) {
  constexpr int KT = 16;
  __shared__ float xs[128][KT + 1];
  __shared__ float wS[KT][64];
  const int tid = threadIdx.x;
  const int row0 = blockIdx.x * 128;
  const int cb0 = blockIdx.y * 64;
  const int cg = tid & 15, rg = tid >> 4;
  const int c0 = cg * 4, r0 = rg * 8;
  float acc[8][4] = {};
  for (int k0 = 0; k0 < K; k0 += KT) {
    for (int idx = tid; idx < 128 * KT; idx += 256) {
      int k = idx & 15, r = idx >> 4;
      int rr = row0 + r; if (rr >= NNODES) rr = NNODES - 1;
      xs[r][k] = X[(size_t)rr * ldx + k0 + k];
    }
    for (int idx = tid; idx < KT * 64; idx += 256) {
      int k = idx >> 6, c = idx & 63;
      wS[k][c] = W[(size_t)(k0 + k) * D + cb0 + c];
    }
    __syncthreads();
#pragma unroll
    for (int kk = 0; kk < KT; ++kk) {
      float xv[8];
#pragma unroll
      for (int i = 0; i < 8; ++i) xv[i] = xs[r0 + i][kk];
      const float4 wv = *(const float4*)&wS[kk][c0];
      float wvv[4] = {wv.x, wv.y, wv.z, wv.w};
#pragma unroll
      for (int i = 0; i < 8; ++i) {
#pragma unroll
        for (int j = 0; j < 4; ++j) acc[i][j] = fmaf(xv[i], wvv[j], acc[i][j]);
      }
    }
    __syncthreads();
  }
  float bv[4];
#pragma unroll
  for (int j = 0; j < 4; ++j) bv[j] = b[cb0 + c0 + j];
#pragma unroll
  for (int i = 0; i < 8; ++i) {
    int rr = row0 + r0 + i;
    if (rr < NNODES) {
#pragma unroll
      for (int j = 0; j < 4; ++j) {
        float v = acc[i][j] + bv[j];
        if (RELU) v = fmaxf(v, 0.0f);
        Y[(size_t)rr * D + cb0 + c0 + j] = v;
      }
    }
  }
}

// Final 256 -> 4 projection.
__global__ __launch_bounds__(256) void final_kernel(
    const float* __restrict__ X, const float* __restrict__ W,
    const float* __restrict__ b, float* __restrict__ out) {
  __shared__ float as[64][65];
  __shared__ float ws3[256][4];
  __shared__ float bs[4];
  const int tid = threadIdx.x;
  const int row0 = blockIdx.x * 64;
  for (int idx = tid; idx < 256 * 4; idx += 256) ws3[idx >> 2][idx & 3] = W[idx];
  if (tid < 4) bs[tid] = b[tid];
  const int r = tid >> 2, c = tid & 3;
  float acc = 0.0f;
  for (int k0 = 0; k0 < 256; k0 += 64) {
    __syncthreads();
    for (int idx = tid; idx < 64 * 64; idx += 256) {
      int r2 = idx >> 6, k = idx & 63;
      int rr = row0 + r2; if (rr >= NNODES) rr = NNODES - 1;
      as[r2][k] = X[(size_t)rr * 256 + k0 + k];
    }
    __syncthreads();
#pragma unroll
    for (int kk = 0; kk < 64; ++kk) acc = fmaf(as[r][kk], ws3[k0 + kk][c], acc);
  }
  int rr = row0 + r;
  if (rr < NNODES) out[(size_t)rr * 4 + c] = acc + bs[c];
}

extern "C" void kernel_launch(void* const* d_in, const int* in_sizes, int n_in,
                              void* d_out, int out_size, void* d_ws, size_t ws_size,
                              hipStream_t stream) {
  const float* x = (const float*)d_in[0];
  const int* eidx = (const int*)d_in[1];  // int32
  const float* w1a = (const float*)d_in[3];
  const float* b1a = (const float*)d_in[4];
  const float* w1b = (const float*)d_in[5];
  const float* b1b = (const float*)d_in[6];
  const float* w2a = (const float*)d_in[7];
  const float* b2a = (const float*)d_in[8];
  const float* w2b = (const float*)d_in[9];
  const float* b2b = (const float*)d_in[10];
  const float* w3a = (const float*)d_in[11];
  const float* b3a = (const float*)d_in[12];
  const float* w3b = (const float*)d_in[13];
  const float* b3b = (const float*)d_in[14];
  const float* wm1 = (const float*)d_in[15];
  const float* bm1 = (const float*)d_in[16];
  const float* wm2 = (const float*)d_in[17];
  const float* bm2 = (const float*)d_in[18];
  const float* wm3 = (const float*)d_in[19];
  const float* bm3 = (const float*)d_in[20];
  float* out = (float*)d_out;

  // Workspace (floats): hcat[N*448] | P[N*256] | Q[N*256] | agg[N*256] | sedge[E]
  // deg/cur overlay agg (CSR build happens before agg init). mh1 overlays P+Q;
  // mh2 overlays agg. Transposed-f16 weights live in d_out (dead until final_kernel).
  float* wsf = (float*)d_ws;
  float* hcat = wsf;
  float* P = wsf + (size_t)NNODES * 448;
  float* Q = P + (size_t)NNODES * 256;
  unsigned* agg = (unsigned*)(Q + (size_t)NNODES * 256);
  unsigned* sedge = agg + (size_t)NNODES * 256;
  int* deg = (int*)agg;
  int* cur = deg + NNODES;
  float* mh1 = P;
  float* mh2 = (float*)agg;
  _Float16* w1h = (_Float16*)d_out;        // 64*64   = 4096 halves
  _Float16* w2h = w1h + 4096;              // 128*128 = 16384
  _Float16* w3h = w2h + 16384;             // 256*256 = 65536 -> total 172 KB < 480 KB

  const int ROWB64 = (NNODES + 63) / 64;     // 469
  const int ROWB128 = (NNODES + 127) / 128;  // 235
  const int EB = (NEDGES + 255) / 256;

  // ---- Build dst-sorted edge list (CSR order), reused by all 3 layers
  fill_u32<<<(NNODES + 255) / 256, 256, 0, stream>>>((unsigned*)deg, NNODES, 0u);
  hist_kernel<<<EB, 256, 0, stream>>>(eidx, deg);
  scan_kernel<<<1, 1024, 0, stream>>>(deg, cur);
  scatter_kernel<<<EB, 256, 0, stream>>>(eidx, cur, sedge);
  // ---- f16 transposed weights (into d_out scratch)
  cvt_wT<<<(64 * 64 + 255) / 256, 256, 0, stream>>>(w1b, w1h, 64);
  cvt_wT<<<(128 * 128 + 255) / 256, 256, 0, stream>>>(w2b, w2h, 128);
  cvt_wT<<<(256 * 256 + 255) / 256, 256, 0, stream>>>(w3b, w3h, 256);

  // ---- EdgeConv 1: C=3 -> 64
  {
    int total = NNODES * 64;
    fill_u32<<<(total + 255) / 256, 256, 0, stream>>>(agg, total, ENC_NEGINF);
    pq_kernel<3, 64><<<dim3(ROWB64, 1), 256, 0, stream>>>(x, 3, 0, w1a, b1a, P, Q);
    edge_mfma<64><<<NEDGES / 64, 256, 0, stream>>>(sedge, P, Q, w1h, b1b, agg);
    decode_kernel<<<(total + 255) / 256, 256, 0, stream>>>(agg, hcat + 0, 6, total);
  }
  // ---- EdgeConv 2: C=64 -> 128
  {
    int total = NNODES * 128;
    fill_u32<<<(total + 255) / 256, 256, 0, stream>>>(agg, total, ENC_NEGINF);
    pq_kernel<64, 128><<<dim3(ROWB64, 2), 256, 0, stream>>>(hcat, 448, 0, w2a, b2a, P, Q);
    edge_mfma<128><<<NEDGES / 64, 256, 0, stream>>>(sedge, P, Q, w2h, b2b, agg);
    decode_kernel<<<(total + 255) / 256, 256, 0, stream>>>(agg, hcat + 64, 7, total);
  }
  // ---- EdgeConv 3: C=128 -> 256
  {
    int total = NNODES * 256;
    fill_u32<<<(total + 255) / 256, 256, 0, stream>>>(agg, total, ENC_NEGINF);
    pq_kernel<128, 256><<<dim3(ROWB64, 4), 256, 0, stream>>>(hcat, 448, 64, w3a, b3a, P, Q);
    edge_mfma<256><<<NEDGES / 64, 256, 0, stream>>>(sedge, P, Q, w3h, b3b, agg);
    decode_kernel<<<(total + 255) / 256, 256, 0, stream>>>(agg, hcat + 192, 8, total);
  }
  // ---- MLP head
  mlp_kernel<448, 512, true><<<dim3(ROWB128, 8), 256, 0, stream>>>(hcat, 448, wm1, bm1, mh1);
  mlp_kernel<512, 256, true><<<dim3(ROWB128, 4), 256, 0, stream>>>(mh1, 512, wm2, bm2, mh2);
  final_kernel<<<ROWB64, 256, 0, stream>>>(mh2, wm3, bm3, out);
}

// Round 5
// 720.631 us; speedup vs baseline: 6.4808x; 1.5087x over previous
//
#include <hip/hip_runtime.h>
#include <cstdint>
#include <cstddef>
#include <math.h>

#define NNODES 30000
#define NEDGES 480000

typedef _Float16 f16x8 __attribute__((ext_vector_type(8)));
typedef float f32x4 __attribute__((ext_vector_type(4)));

constexpr unsigned ENC_NEGINF = 0x007FFFFFu;  // encode(-inf)

__device__ __forceinline__ unsigned enc_f32(float f) {
  unsigned u = __float_as_uint(f);
  return (u & 0x80000000u) ? ~u : (u | 0x80000000u);
}
__device__ __forceinline__ float dec_f32(unsigned e) {
  unsigned u = (e & 0x80000000u) ? (e ^ 0x80000000u) : ~e;
  return __uint_as_float(u);
}

__global__ void fill_u32(unsigned* __restrict__ p, int n, unsigned v) {
  int i = blockIdx.x * 256 + threadIdx.x;
  if (i < n) p[i] = v;
}

// ---- CSR build: histogram -> exclusive scan -> scatter (sorted by dst) ----
__global__ void hist_kernel(const int* __restrict__ eidx, int* __restrict__ deg) {
  int e = blockIdx.x * 256 + threadIdx.x;
  if (e < NEDGES) atomicAdd(&deg[eidx[NEDGES + e]], 1);
}

__global__ __launch_bounds__(1024) void scan_kernel(const int* __restrict__ deg,
                                                    int* __restrict__ cur) {
  __shared__ int part[1024];
  const int tid = threadIdx.x;
  constexpr int PER = 30;  // 1024*30 = 30720 >= 30000
  int loc[PER];
  int s = 0;
  const int base = tid * PER;
#pragma unroll
  for (int i = 0; i < PER; ++i) {
    int idx = base + i;
    int v = (idx < NNODES) ? deg[idx] : 0;
    loc[i] = s;
    s += v;
  }
  part[tid] = s;
  __syncthreads();
  for (int d = 1; d < 1024; d <<= 1) {
    int t = (tid >= d) ? part[tid - d] : 0;
    __syncthreads();
    part[tid] += t;
    __syncthreads();
  }
  const int excl = part[tid] - s;
#pragma unroll
  for (int i = 0; i < PER; ++i) {
    int idx = base + i;
    if (idx < NNODES) cur[idx] = excl + loc[i];
  }
}

// Pack (dst<<16)|src — both < 30000 < 65536.
__global__ void scatter_kernel(const int* __restrict__ eidx, int* __restrict__ cur,
                               unsigned* __restrict__ sedge) {
  int e = blockIdx.x * 256 + threadIdx.x;
  if (e < NEDGES) {
    int s = eidx[e], d = eidx[NEDGES + e];
    int pos = atomicAdd(&cur[d], 1);
    sedge[pos] = ((unsigned)d << 16) | (unsigned)s;
  }
}

// Transposed f16 weight: BT[n*K + k] = (f16) W[k*N + n]  (W is [K,N])
__global__ void cvt_wT(const float* __restrict__ W, _Float16* __restrict__ BT,
                       int Kd, int Nd) {
  int idx = blockIdx.x * 256 + threadIdx.x;
  if (idx < Kd * Nd) {
    int k = idx / Nd, n = idx % Nd;  // coalesced read of W[k][n]
    BT[(size_t)n * Kd + k] = (_Float16)W[idx];
  }
}

// fp32 -> f16 elementwise (n divisible by 4)
__global__ void cvt_f16(const float* __restrict__ X, _Float16* __restrict__ Y, int n4) {
  int i = blockIdx.x * 256 + threadIdx.x;
  if (i < n4) {
    float4 v = *(const float4*)&X[i * 4];
    union { _Float16 h[4]; float2 f2; } u;
    u.h[0] = (_Float16)v.x; u.h[1] = (_Float16)v.y;
    u.h[2] = (_Float16)v.z; u.h[3] = (_Float16)v.w;
    *(float2*)&Y[i * 4] = u.f2;
  }
}

// Decode encoded max-agg into hcat slice (hc already offset by column).
__global__ void decode_kernel(const unsigned* __restrict__ agg, float* __restrict__ hc,
                              int shift, int total) {
  int i = blockIdx.x * 256 + threadIdx.x;
  if (i < total) {
    unsigned e = agg[i];
    float v = (e == ENC_NEGINF) ? 0.0f : dec_f32(e);
    int r = i >> shift;
    int c = i & ((1 << shift) - 1);
    hc[(size_t)r * 448 + c] = v;
  }
}

// P[n] = x[n] @ (W1_top - W1_bot) + b1 ; Q[n] = x[n] @ W1_bot
template <int K, int D>
__global__ __launch_bounds__(256) void pq_kernel(
    const float* __restrict__ X, int ldx, int koff,
    const float* __restrict__ W1, const float* __restrict__ b1,
    float* __restrict__ P, float* __restrict__ Q) {
  constexpr int KT = 16;
  __shared__ float xs[64][KT + 1];
  __shared__ float wt[KT][64];
  __shared__ float wb[KT][64];
  const int tid = threadIdx.x;
  const int row0 = blockIdx.x * 64;
  const int cb0 = blockIdx.y * 64;
  const int cg = tid & 15, rg = tid >> 4;
  const int c0 = cg * 4, r0 = rg * 4;
  float p[4][4] = {}, q[4][4] = {};
  for (int k0 = 0; k0 < K; k0 += KT) {
    const int kt = (K - k0 < KT) ? (K - k0) : KT;
    for (int idx = tid; idx < 64 * KT; idx += 256) {
      int k = idx & (KT - 1), r = idx >> 4;
      if (k < kt) {
        int rr = row0 + r; if (rr >= NNODES) rr = NNODES - 1;
        xs[r][k] = X[(size_t)rr * ldx + koff + k0 + k];
      }
    }
    for (int idx = tid; idx < KT * 64; idx += 256) {
      int k = idx >> 6, c = idx & 63;
      if (k < kt) {
        wt[k][c] = W1[(size_t)(k0 + k) * D + cb0 + c];
        wb[k][c] = W1[(size_t)(K + k0 + k) * D + cb0 + c];
      }
    }
    __syncthreads();
    for (int kk = 0; kk < kt; ++kk) {
      float xv[4];
#pragma unroll
      for (int i = 0; i < 4; ++i) xv[i] = xs[r0 + i][kk];
      const float4 wtv = *(const float4*)&wt[kk][c0];
      const float4 wbv = *(const float4*)&wb[kk][c0];
      float dv[4] = {wtv.x - wbv.x, wtv.y - wbv.y, wtv.z - wbv.z, wtv.w - wbv.w};
      float bv[4] = {wbv.x, wbv.y, wbv.z, wbv.w};
#pragma unroll
      for (int i = 0; i < 4; ++i) {
#pragma unroll
        for (int j = 0; j < 4; ++j) {
          p[i][j] = fmaf(xv[i], dv[j], p[i][j]);
          q[i][j] = fmaf(xv[i], bv[j], q[i][j]);
        }
      }
    }
    __syncthreads();
  }
  float b1v[4];
#pragma unroll
  for (int j = 0; j < 4; ++j) b1v[j] = b1[cb0 + c0 + j];
#pragma unroll
  for (int i = 0; i < 4; ++i) {
    int rr = row0 + r0 + i;
    if (rr < NNODES) {
#pragma unroll
      for (int j = 0; j < 4; ++j) {
        P[(size_t)rr * D + cb0 + c0 + j] = p[i][j] + b1v[j];
        Q[(size_t)rr * D + cb0 + c0 + j] = q[i][j];
      }
    }
  }
}

// MFMA edge kernel (dst-sorted edges): t1 = relu(P[dst]+Q[src]) -> f16 LDS;
// y = t1 @ W2 via v_mfma_f32_16x16x32_f16 (fp32 acc); +b2; in-block segmented
// max over sorted dst; few atomicMax to agg.
template <int D>
__global__ __launch_bounds__(256) void edge_mfma(
    const unsigned* __restrict__ sedge,
    const float* __restrict__ P, const float* __restrict__ Q,
    const _Float16* __restrict__ BT,  // [n][k] f16 transposed W2
    const float* __restrict__ b2,
    unsigned* __restrict__ agg) {
  constexpr int BE = 64;                 // edges per block
  constexpr int MT = 4;                  // M(edge)-tiles of 16
  constexpr int NT = D / 64;             // N-tiles per wave
  constexpr int SA = D + 8;              // A stride in halves (+8 kills bank conflicts)
  constexpr bool STAGED = (D == 256);
  constexpr int SB = STAGED ? 40 : (D + 8);
  constexpr int KS = 32;                 // K per MFMA step
  constexpr int NSTEP = D / KS;
  constexpr int ABYTES = BE * SA * 2;
  constexpr int BROWS = STAGED ? 256 : D;
  constexpr int BBYTES = BROWS * SB * 2;
  __shared__ __align__(16) char smem[ABYTES + BBYTES];
  __shared__ int sSrc[BE], sDst[BE];
  _Float16* Abuf = (_Float16*)smem;
  _Float16* Bbuf = (_Float16*)(smem + ABYTES);
  float* ybuf = (float*)smem;            // overlays A(+B) after GEMM

  const int tid = threadIdx.x;
  const int wave = tid >> 6, lane = tid & 63;
  const int l16 = lane & 15, quad = lane >> 4;
  const int ebase = blockIdx.x * BE;
  if (tid < BE) {
    unsigned pk = sedge[ebase + tid];
    sSrc[tid] = (int)(pk & 0xFFFFu);
    sDst[tid] = (int)(pk >> 16);
  }
  __syncthreads();
  // ---- Phase A: t1 (f16) into Abuf[e][k]
  {
    const int e = tid >> 2, qd = tid & 3;
    const float* Pr = P + (size_t)sDst[e] * D;
    const float* Qr = Q + (size_t)sSrc[e] * D;
#pragma unroll
    for (int t = 0; t < D / 32; ++t) {
      int k = (qd + 4 * t) * 8;
      float4 p0 = *(const float4*)(Pr + k);
      float4 p1 = *(const float4*)(Pr + k + 4);
      float4 q0 = *(const float4*)(Qr + k);
      float4 q1 = *(const float4*)(Qr + k + 4);
      union { _Float16 h[8]; float4 f4; } u;
      u.h[0] = (_Float16)fmaxf(p0.x + q0.x, 0.0f);
      u.h[1] = (_Float16)fmaxf(p0.y + q0.y, 0.0f);
      u.h[2] = (_Float16)fmaxf(p0.z + q0.z, 0.0f);
      u.h[3] = (_Float16)fmaxf(p0.w + q0.w, 0.0f);
      u.h[4] = (_Float16)fmaxf(p1.x + q1.x, 0.0f);
      u.h[5] = (_Float16)fmaxf(p1.y + q1.y, 0.0f);
      u.h[6] = (_Float16)fmaxf(p1.z + q1.z, 0.0f);
      u.h[7] = (_Float16)fmaxf(p1.w + q1.w, 0.0f);
      *(float4*)&Abuf[e * SA + k] = u.f4;
    }
  }
  // ---- Phase B: GEMM
  f32x4 acc[MT][NT] = {};
  auto kstep = [&](int ka, int kb) {
    f16x8 af[MT], bf[NT];
#pragma unroll
    for (int mt = 0; mt < MT; ++mt)
      af[mt] = *(const f16x8*)&Abuf[(mt * 16 + l16) * SA + ka + quad * 8];
#pragma unroll
    for (int nt = 0; nt < NT; ++nt)
      bf[nt] = *(const f16x8*)&Bbuf[(wave * NT * 16 + nt * 16 + l16) * SB + kb + quad * 8];
#pragma unroll
    for (int mt = 0; mt < MT; ++mt)
#pragma unroll
      for (int nt = 0; nt < NT; ++nt)
        acc[mt][nt] = __builtin_amdgcn_mfma_f32_16x16x32_f16(af[mt], bf[nt], acc[mt][nt], 0, 0, 0);
  };
  if (!STAGED) {
    constexpr int CH = D / 8;
    for (int idx = tid; idx < D * CH; idx += 256) {
      int n = idx / CH, cc = idx % CH;
      *(float4*)&Bbuf[n * SB + cc * 8] = *(const float4*)&BT[(size_t)n * D + cc * 8];
    }
    __syncthreads();  // covers Abuf + Bbuf
    for (int ks = 0; ks < NSTEP; ++ks) kstep(ks * KS, ks * KS);
  } else {
    for (int ks = 0; ks < NSTEP; ++ks) {
      __syncthreads();  // prev slice consumed (first iter: Abuf ready)
      for (int i = 0; i < 4; ++i) {
        int idx = i * 256 + tid;
        int n = idx >> 2, cc = idx & 3;
        *(float4*)&Bbuf[n * SB + cc * 8] = *(const float4*)&BT[(size_t)n * 256 + ks * KS + cc * 8];
      }
      __syncthreads();
      kstep(ks * KS, 0);
    }
  }
  // ---- Phase C: +bias, segmented max over sorted dst, atomics
  constexpr int HALVES = STAGED ? 2 : 1;
  constexpr int CPH = D / HALVES;        // cols per half
  constexpr int WPH = 4 / HALVES;        // waves per half
  constexpr int SL = BE * CPH / 256;     // edges per scan slice
  for (int h = 0; h < HALVES; ++h) {
    __syncthreads();
    if (wave / WPH == h) {
#pragma unroll
      for (int mt = 0; mt < MT; ++mt)
#pragma unroll
        for (int nt = 0; nt < NT; ++nt) {
          int ng = wave * NT * 16 + nt * 16 + l16;
          float bias = b2[ng];
          int nl = ng - h * CPH;
#pragma unroll
          for (int r = 0; r < 4; ++r)
            ybuf[nl * (BE + 1) + mt * 16 + quad * 4 + r] = acc[mt][nt][r] + bias;
        }
    }
    __syncthreads();
    {
      const int c = tid % CPH, g = tid / CPH;
      const int es = g * SL;
      float run = -INFINITY;
      int pd = sDst[es];
      for (int e = es; e < es + SL; ++e) {
        int d = sDst[e];
        if (d != pd) {
          atomicMax(&agg[(size_t)pd * D + h * CPH + c], enc_f32(run));
          run = -INFINITY;
          pd = d;
        }
        run = fmaxf(run, ybuf[c * (BE + 1) + e]);
      }
      atomicMax(&agg[(size_t)pd * D + h * CPH + c], enc_f32(run));
    }
  }
}

// MFMA MLP GEMM: Y = act(Xh @ W + b). Block: 64 rows x 128 cols; 4 waves,
// each wave 64x32 (MT=4, NT=2). Xh [M,K] f16; BT [NTOT,K] f16; fp32 acc.
template <int K, int NTOT, bool RELU, bool OUTF16>
__global__ __launch_bounds__(256) void mlp_mfma(
    const _Float16* __restrict__ Xh, const _Float16* __restrict__ BT,
    const float* __restrict__ bias, void* __restrict__ Yv) {
  constexpr int KT = 64;
  constexpr int SA = KT + 8;  // 72
  __shared__ __align__(16) _Float16 As[64 * SA];
  __shared__ __align__(16) _Float16 Bs[128 * SA];
  const int tid = threadIdx.x;
  const int wave = tid >> 6, lane = tid & 63;
  const int l16 = lane & 15, quad = lane >> 4;
  const int row0 = blockIdx.x * 64;
  const int cb0 = blockIdx.y * 128;
  f32x4 acc[4][2] = {};
  for (int k0 = 0; k0 < K; k0 += KT) {
    __syncthreads();
    for (int idx = tid; idx < 512; idx += 256) {
      int r = idx >> 3, cc = idx & 7;
      int rr = row0 + r; if (rr >= NNODES) rr = NNODES - 1;
      *(float4*)&As[r * SA + cc * 8] = *(const float4*)&Xh[(size_t)rr * K + k0 + cc * 8];
    }
    for (int idx = tid; idx < 1024; idx += 256) {
      int n = idx >> 3, cc = idx & 7;
      *(float4*)&Bs[n * SA + cc * 8] = *(const float4*)&BT[(size_t)(cb0 + n) * K + k0 + cc * 8];
    }
    __syncthreads();
#pragma unroll
    for (int kh = 0; kh < 2; ++kh) {
      f16x8 af[4], bf[2];
#pragma unroll
      for (int mt = 0; mt < 4; ++mt)
        af[mt] = *(const f16x8*)&As[(mt * 16 + l16) * SA + kh * 32 + quad * 8];
#pragma unroll
      for (int nt = 0; nt < 2; ++nt)
        bf[nt] = *(const f16x8*)&Bs[(wave * 32 + nt * 16 + l16) * SA + kh * 32 + quad * 8];
#pragma unroll
      for (int mt = 0; mt < 4; ++mt)
#pragma unroll
        for (int nt = 0; nt < 2; ++nt)
          acc[mt][nt] = __builtin_amdgcn_mfma_f32_16x16x32_f16(af[mt], bf[nt], acc[mt][nt], 0, 0, 0);
    }
  }
#pragma unroll
  for (int nt = 0; nt < 2; ++nt) {
    int n = cb0 + wave * 32 + nt * 16 + l16;
    float bv = bias[n];
#pragma unroll
    for (int mt = 0; mt < 4; ++mt) {
#pragma unroll
      for (int r = 0; r < 4; ++r) {
        int m = row0 + mt * 16 + quad * 4 + r;
        if (m < NNODES) {
          float v = acc[mt][nt][r] + bv;
          if (RELU) v = fmaxf(v, 0.0f);
          if (OUTF16) ((_Float16*)Yv)[(size_t)m * NTOT + n] = (_Float16)v;
          else ((float*)Yv)[(size_t)m * NTOT + n] = v;
        }
      }
    }
  }
}

// Final 256 -> 4 projection.
__global__ __launch_bounds__(256) void final_kernel(
    const float* __restrict__ X, const float* __restrict__ W,
    const float* __restrict__ b, float* __restrict__ out) {
  __shared__ float as[64][65];
  __shared__ float ws3[256][4];
  __shared__ float bs[4];
  const int tid = threadIdx.x;
  const int row0 = blockIdx.x * 64;
  for (int idx = tid; idx < 256 * 4; idx += 256) ws3[idx >> 2][idx & 3] = W[idx];
  if (tid < 4) bs[tid] = b[tid];
  const int r = tid >> 2, c = tid & 3;
  float acc = 0.0f;
  for (int k0 = 0; k0 < 256; k0 += 64) {
    __syncthreads();
    for (int idx = tid; idx < 64 * 64; idx += 256) {
      int r2 = idx >> 6, k = idx & 63;
      int rr = row0 + r2; if (rr >= NNODES) rr = NNODES - 1;
      as[r2][k] = X[(size_t)rr * 256 + k0 + k];
    }
    __syncthreads();
#pragma unroll
    for (int kk = 0; kk < 64; ++kk) acc = fmaf(as[r][kk], ws3[k0 + kk][c], acc);
  }
  int rr = row0 + r;
  if (rr < NNODES) out[(size_t)rr * 4 + c] = acc + bs[c];
}

extern "C" void kernel_launch(void* const* d_in, const int* in_sizes, int n_in,
                              void* d_out, int out_size, void* d_ws, size_t ws_size,
                              hipStream_t stream) {
  const float* x = (const float*)d_in[0];
  const int* eidx = (const int*)d_in[1];  // int32
  const float* w1a = (const float*)d_in[3];
  const float* b1a = (const float*)d_in[4];
  const float* w1b = (const float*)d_in[5];
  const float* b1b = (const float*)d_in[6];
  const float* w2a = (const float*)d_in[7];
  const float* b2a = (const float*)d_in[8];
  const float* w2b = (const float*)d_in[9];
  const float* b2b = (const float*)d_in[10];
  const float* w3a = (const float*)d_in[11];
  const float* b3a = (const float*)d_in[12];
  const float* w3b = (const float*)d_in[13];
  const float* b3b = (const float*)d_in[14];
  const float* wm1 = (const float*)d_in[15];
  const float* bm1 = (const float*)d_in[16];
  const float* wm2 = (const float*)d_in[17];
  const float* bm2 = (const float*)d_in[18];
  const float* wm3 = (const float*)d_in[19];
  const float* bm3 = (const float*)d_in[20];
  float* out = (float*)d_out;

  // Workspace (floats): hcat[N*448] | P[N*256] | Q[N*256] | agg[N*256] | sedge[E]
  // Overlays: deg/cur on agg (CSR build, pre-init); hcat_h (f16) on P after layer 3;
  // mh1h (f16, 512N halves) on Q (exact fit); mh2 fp32 on agg; wm1h (f16) on hcat
  // (after hcat->f16 conversion). Edge weights + wm2h live in d_out (434 KB < 480 KB).
  float* wsf = (float*)d_ws;
  float* hcat = wsf;
  float* P = wsf + (size_t)NNODES * 448;
  float* Q = P + (size_t)NNODES * 256;
  unsigned* agg = (unsigned*)(Q + (size_t)NNODES * 256);
  unsigned* sedge = agg + (size_t)NNODES * 256;
  int* deg = (int*)agg;
  int* cur = deg + NNODES;
  _Float16* hcat_h = (_Float16*)P;
  _Float16* mh1h = (_Float16*)Q;
  float* mh2 = (float*)agg;
  _Float16* wm1h = (_Float16*)hcat;
  _Float16* w1h = (_Float16*)d_out;        // 64*64   = 4096 halves
  _Float16* w2h = w1h + 4096;              // 128*128 = 16384
  _Float16* w3h = w2h + 16384;             // 256*256 = 65536
  _Float16* wm2h = w3h + 65536;            // 256*512 = 131072 -> total 434 KB

  const int ROWB64 = (NNODES + 63) / 64;     // 469
  const int EB = (NEDGES + 255) / 256;

  // ---- Build dst-sorted edge list (CSR order), reused by all 3 layers
  fill_u32<<<(NNODES + 255) / 256, 256, 0, stream>>>((unsigned*)deg, NNODES, 0u);
  hist_kernel<<<EB, 256, 0, stream>>>(eidx, deg);
  scan_kernel<<<1, 1024, 0, stream>>>(deg, cur);
  scatter_kernel<<<EB, 256, 0, stream>>>(eidx, cur, sedge);
  // ---- f16 transposed weights (into d_out scratch)
  cvt_wT<<<(64 * 64 + 255) / 256, 256, 0, stream>>>(w1b, w1h, 64, 64);
  cvt_wT<<<(128 * 128 + 255) / 256, 256, 0, stream>>>(w2b, w2h, 128, 128);
  cvt_wT<<<(256 * 256 + 255) / 256, 256, 0, stream>>>(w3b, w3h, 256, 256);
  cvt_wT<<<(512 * 256 + 255) / 256, 256, 0, stream>>>(wm2, wm2h, 512, 256);

  // ---- EdgeConv 1: C=3 -> 64
  {
    int total = NNODES * 64;
    fill_u32<<<(total + 255) / 256, 256, 0, stream>>>(agg, total, ENC_NEGINF);
    pq_kernel<3, 64><<<dim3(ROWB64, 1), 256, 0, stream>>>(x, 3, 0, w1a, b1a, P, Q);
    edge_mfma<64><<<NEDGES / 64, 256, 0, stream>>>(sedge, P, Q, w1h, b1b, agg);
    decode_kernel<<<(total + 255) / 256, 256, 0, stream>>>(agg, hcat + 0, 6, total);
  }
  // ---- EdgeConv 2: C=64 -> 128
  {
    int total = NNODES * 128;
    fill_u32<<<(total + 255) / 256, 256, 0, stream>>>(agg, total, ENC_NEGINF);
    pq_kernel<64, 128><<<dim3(ROWB64, 2), 256, 0, stream>>>(hcat, 448, 0, w2a, b2a, P, Q);
    edge_mfma<128><<<NEDGES / 64, 256, 0, stream>>>(sedge, P, Q, w2h, b2b, agg);
    decode_kernel<<<(total + 255) / 256, 256, 0, stream>>>(agg, hcat + 64, 7, total);
  }
  // ---- EdgeConv 3: C=128 -> 256
  {
    int total = NNODES * 256;
    fill_u32<<<(total + 255) / 256, 256, 0, stream>>>(agg, total, ENC_NEGINF);
    pq_kernel<128, 256><<<dim3(ROWB64, 4), 256, 0, stream>>>(hcat, 448, 64, w3a, b3a, P, Q);
    edge_mfma<256><<<NEDGES / 64, 256, 0, stream>>>(sedge, P, Q, w3h, b3b, agg);
    decode_kernel<<<(total + 255) / 256, 256, 0, stream>>>(agg, hcat + 192, 8, total);
  }
  // ---- MLP head (MFMA f16)
  cvt_f16<<<(NNODES * 448 / 4 + 255) / 256, 256, 0, stream>>>(hcat, hcat_h, NNODES * 448 / 4);
  cvt_wT<<<(448 * 512 + 255) / 256, 256, 0, stream>>>(wm1, wm1h, 448, 512);  // hcat now dead
  mlp_mfma<448, 512, true, true><<<dim3(ROWB64, 4), 256, 0, stream>>>(hcat_h, wm1h, bm1, mh1h);
  mlp_mfma<512, 256, true, false><<<dim3(ROWB64, 2), 256, 0, stream>>>(mh1h, wm2h, bm2, mh2);
  final_kernel<<<ROWB64, 256, 0, stream>>>(mh2, wm3, bm3, out);
}

// Round 6
// 703.359 us; speedup vs baseline: 6.6399x; 1.0246x over previous
//
#include <hip/hip_runtime.h>
#include <cstdint>
#include <cstddef>
#include <math.h>

#define NNODES 30000
#define NEDGES 480000

typedef _Float16 f16x8 __attribute__((ext_vector_type(8)));
typedef float f32x4 __attribute__((ext_vector_type(4)));

constexpr unsigned ENC_NEGINF = 0x007FFFFFu;  // encode(-inf)

__device__ __forceinline__ unsigned enc_f32(float f) {
  unsigned u = __float_as_uint(f);
  return (u & 0x80000000u) ? ~u : (u | 0x80000000u);
}
__device__ __forceinline__ float dec_f32(unsigned e) {
  unsigned u = (e & 0x80000000u) ? (e ^ 0x80000000u) : ~e;
  return __uint_as_float(u);
}

__global__ void fill_u32(unsigned* __restrict__ p, int n, unsigned v) {
  int i = blockIdx.x * 256 + threadIdx.x;
  if (i < n) p[i] = v;
}

// ---- CSR build: histogram -> exclusive scan -> scatter (sorted by dst) ----
__global__ void hist_kernel(const int* __restrict__ eidx, int* __restrict__ deg) {
  int e = blockIdx.x * 256 + threadIdx.x;
  if (e < NEDGES) atomicAdd(&deg[eidx[NEDGES + e]], 1);
}

__global__ __launch_bounds__(1024) void scan_kernel(const int* __restrict__ deg,
                                                    int* __restrict__ cur) {
  __shared__ int part[1024];
  const int tid = threadIdx.x;
  constexpr int PER = 30;  // 1024*30 = 30720 >= 30000
  int loc[PER];
  int s = 0;
  const int base = tid * PER;
#pragma unroll
  for (int i = 0; i < PER; ++i) {
    int idx = base + i;
    int v = (idx < NNODES) ? deg[idx] : 0;
    loc[i] = s;
    s += v;
  }
  part[tid] = s;
  __syncthreads();
  for (int d = 1; d < 1024; d <<= 1) {
    int t = (tid >= d) ? part[tid - d] : 0;
    __syncthreads();
    part[tid] += t;
    __syncthreads();
  }
  const int excl = part[tid] - s;
#pragma unroll
  for (int i = 0; i < PER; ++i) {
    int idx = base + i;
    if (idx < NNODES) cur[idx] = excl + loc[i];
  }
}

// Pack (dst<<16)|src — both < 30000 < 65536.
__global__ void scatter_kernel(const int* __restrict__ eidx, int* __restrict__ cur,
                               unsigned* __restrict__ sedge) {
  int e = blockIdx.x * 256 + threadIdx.x;
  if (e < NEDGES) {
    int s = eidx[e], d = eidx[NEDGES + e];
    int pos = atomicAdd(&cur[d], 1);
    sedge[pos] = ((unsigned)d << 16) | (unsigned)s;
  }
}

// Transposed f16 weight: BT[n*K + k] = (f16) W[k*N + n]  (W is [K,N]) — MLP path.
__global__ void cvt_wT(const float* __restrict__ W, _Float16* __restrict__ BT,
                       int Kd, int Nd) {
  int idx = blockIdx.x * 256 + threadIdx.x;
  if (idx < Kd * Nd) {
    int k = idx / Nd, n = idx % Nd;  // coalesced read of W[k][n]
    BT[(size_t)n * Kd + k] = (_Float16)W[idx];
  }
}

// Edge weight -> MFMA-fragment order: Bf[((ks*NTILES + tile)*64 + lane)*8 + j]
// = W[k][n], n = tile*16 + (lane&15), k = ks*32 + (lane>>4)*8 + j.
__global__ void cvt_bfrag(const float* __restrict__ W, _Float16* __restrict__ Bf, int Dd) {
  int idx = blockIdx.x * 256 + threadIdx.x;
  if (idx >= Dd * Dd) return;
  int j = idx & 7;
  int lane = (idx >> 3) & 63;
  int rest = idx >> 9;  // ks*NTILES + tile
  int ntiles = Dd >> 4;
  int ks = rest / ntiles, tile = rest % ntiles;
  int n = tile * 16 + (lane & 15);
  int k = ks * 32 + (lane >> 4) * 8 + j;
  Bf[idx] = (_Float16)W[(size_t)k * Dd + n];
}

// fp32 -> f16 elementwise (n divisible by 4)
__global__ void cvt_f16(const float* __restrict__ X, _Float16* __restrict__ Y, int n4) {
  int i = blockIdx.x * 256 + threadIdx.x;
  if (i < n4) {
    float4 v = *(const float4*)&X[i * 4];
    union { _Float16 h[4]; float2 f2; } u;
    u.h[0] = (_Float16)v.x; u.h[1] = (_Float16)v.y;
    u.h[2] = (_Float16)v.z; u.h[3] = (_Float16)v.w;
    *(float2*)&Y[i * 4] = u.f2;
  }
}

// Decode encoded max-agg into hcat slice (hc already offset by column).
__global__ void decode_kernel(const unsigned* __restrict__ agg, float* __restrict__ hc,
                              int shift, int total) {
  int i = blockIdx.x * 256 + threadIdx.x;
  if (i < total) {
    unsigned e = agg[i];
    float v = (e == ENC_NEGINF) ? 0.0f : dec_f32(e);
    int r = i >> shift;
    int c = i & ((1 << shift) - 1);
    hc[(size_t)r * 448 + c] = v;
  }
}

// P[n] = x[n] @ (W1_top - W1_bot) + b1 ; Q[n] = x[n] @ W1_bot
template <int K, int D>
__global__ __launch_bounds__(256) void pq_kernel(
    const float* __restrict__ X, int ldx, int koff,
    const float* __restrict__ W1, const float* __restrict__ b1,
    float* __restrict__ P, float* __restrict__ Q) {
  constexpr int KT = 16;
  __shared__ float xs[64][KT + 1];
  __shared__ float wt[KT][64];
  __shared__ float wb[KT][64];
  const int tid = threadIdx.x;
  const int row0 = blockIdx.x * 64;
  const int cb0 = blockIdx.y * 64;
  const int cg = tid & 15, rg = tid >> 4;
  const int c0 = cg * 4, r0 = rg * 4;
  float p[4][4] = {}, q[4][4] = {};
  for (int k0 = 0; k0 < K; k0 += KT) {
    const int kt = (K - k0 < KT) ? (K - k0) : KT;
    for (int idx = tid; idx < 64 * KT; idx += 256) {
      int k = idx & (KT - 1), r = idx >> 4;
      if (k < kt) {
        int rr = row0 + r; if (rr >= NNODES) rr = NNODES - 1;
        xs[r][k] = X[(size_t)rr * ldx + koff + k0 + k];
      }
    }
    for (int idx = tid; idx < KT * 64; idx += 256) {
      int k = idx >> 6, c = idx & 63;
      if (k < kt) {
        wt[k][c] = W1[(size_t)(k0 + k) * D + cb0 + c];
        wb[k][c] = W1[(size_t)(K + k0 + k) * D + cb0 + c];
      }
    }
    __syncthreads();
    for (int kk = 0; kk < kt; ++kk) {
      float xv[4];
#pragma unroll
      for (int i = 0; i < 4; ++i) xv[i] = xs[r0 + i][kk];
      const float4 wtv = *(const float4*)&wt[kk][c0];
      const float4 wbv = *(const float4*)&wb[kk][c0];
      float dv[4] = {wtv.x - wbv.x, wtv.y - wbv.y, wtv.z - wbv.z, wtv.w - wbv.w};
      float bv[4] = {wbv.x, wbv.y, wbv.z, wbv.w};
#pragma unroll
      for (int i = 0; i < 4; ++i) {
#pragma unroll
        for (int j = 0; j < 4; ++j) {
          p[i][j] = fmaf(xv[i], dv[j], p[i][j]);
          q[i][j] = fmaf(xv[i], bv[j], q[i][j]);
        }
      }
    }
    __syncthreads();
  }
  float b1v[4];
#pragma unroll
  for (int j = 0; j < 4; ++j) b1v[j] = b1[cb0 + c0 + j];
#pragma unroll
  for (int i = 0; i < 4; ++i) {
    int rr = row0 + r0 + i;
    if (rr < NNODES) {
#pragma unroll
      for (int j = 0; j < 4; ++j) {
        P[(size_t)rr * D + cb0 + c0 + j] = p[i][j] + b1v[j];
        Q[(size_t)rr * D + cb0 + c0 + j] = q[i][j];
      }
    }
  }
}

// MFMA edge kernel (dst-sorted edges): t1 = relu(P[dst]+Q[src]) -> f16 LDS;
// y = t1 @ W2 with B fragments loaded straight from global (fragment-ordered,
// L2-resident; no B LDS, no K-loop barriers); +b2; in-block segmented max.
template <int D>
__global__ __launch_bounds__(256) void edge_mfma(
    const unsigned* __restrict__ sedge,
    const float* __restrict__ P, const float* __restrict__ Q,
    const _Float16* __restrict__ Bf,  // fragment-ordered f16 W2
    const float* __restrict__ b2,
    unsigned* __restrict__ agg) {
  constexpr int BE = 64;                 // edges per block
  constexpr int MT = 4;                  // M(edge)-tiles of 16
  constexpr int NT = D / 64;             // N-tiles per wave
  constexpr int NTILES = D / 16;
  constexpr int NSTEP = D / 32;          // K steps of 32
  constexpr int SA = D + 8;              // A stride in halves
  constexpr int HALVES = (D == 64) ? 1 : 2;
  constexpr int CPH = D / HALVES;        // cols per half in phase C
  constexpr int WPH = 4 / HALVES;        // waves per half
  constexpr int SL = BE * CPH / 256;     // edges per scan slice
  constexpr int ABYTES = BE * SA * 2;
  constexpr int YBYTES = CPH * (BE + 1) * 4;
  constexpr int SBYTES = (ABYTES > YBYTES) ? ABYTES : YBYTES;
  __shared__ __align__(16) char smem[SBYTES];
  __shared__ int sSrc[BE], sDst[BE];
  _Float16* Abuf = (_Float16*)smem;
  float* ybuf = (float*)smem;            // overlays A after GEMM

  const int tid = threadIdx.x;
  const int wave = tid >> 6, lane = tid & 63;
  const int l16 = lane & 15, quad = lane >> 4;
  const int ebase = blockIdx.x * BE;
  if (tid < BE) {
    unsigned pk = sedge[ebase + tid];
    sSrc[tid] = (int)(pk & 0xFFFFu);
    sDst[tid] = (int)(pk >> 16);
  }
  __syncthreads();
  // ---- Phase A: t1 (f16) into Abuf[e][k]
  {
    const int e = tid >> 2, qd = tid & 3;
    const float* Pr = P + (size_t)sDst[e] * D;
    const float* Qr = Q + (size_t)sSrc[e] * D;
#pragma unroll
    for (int t = 0; t < D / 32; ++t) {
      int k = (qd + 4 * t) * 8;
      float4 p0 = *(const float4*)(Pr + k);
      float4 p1 = *(const float4*)(Pr + k + 4);
      float4 q0 = *(const float4*)(Qr + k);
      float4 q1 = *(const float4*)(Qr + k + 4);
      union { _Float16 h[8]; float4 f4; } u;
      u.h[0] = (_Float16)fmaxf(p0.x + q0.x, 0.0f);
      u.h[1] = (_Float16)fmaxf(p0.y + q0.y, 0.0f);
      u.h[2] = (_Float16)fmaxf(p0.z + q0.z, 0.0f);
      u.h[3] = (_Float16)fmaxf(p0.w + q0.w, 0.0f);
      u.h[4] = (_Float16)fmaxf(p1.x + q1.x, 0.0f);
      u.h[5] = (_Float16)fmaxf(p1.y + q1.y, 0.0f);
      u.h[6] = (_Float16)fmaxf(p1.z + q1.z, 0.0f);
      u.h[7] = (_Float16)fmaxf(p1.w + q1.w, 0.0f);
      *(float4*)&Abuf[e * SA + k] = u.f4;
    }
  }
  __syncthreads();
  // ---- Phase B: GEMM, B fragments direct from global (no barriers)
  f32x4 acc[MT][NT] = {};
  const _Float16* BfW = Bf + ((size_t)(wave * NT) * 64 + lane) * 8;
#pragma unroll
  for (int ks = 0; ks < NSTEP; ++ks) {
    f16x8 bf[NT], af[MT];
#pragma unroll
    for (int nt = 0; nt < NT; ++nt)
      bf[nt] = *(const f16x8*)(BfW + ((size_t)ks * NTILES + nt) * 64 * 8);
#pragma unroll
    for (int mt = 0; mt < MT; ++mt)
      af[mt] = *(const f16x8*)&Abuf[(mt * 16 + l16) * SA + ks * 32 + quad * 8];
#pragma unroll
    for (int mt = 0; mt < MT; ++mt)
#pragma unroll
      for (int nt = 0; nt < NT; ++nt)
        acc[mt][nt] = __builtin_amdgcn_mfma_f32_16x16x32_f16(af[mt], bf[nt], acc[mt][nt], 0, 0, 0);
  }
  // ---- Phase C: +bias, segmented max over sorted dst, atomics
  for (int h = 0; h < HALVES; ++h) {
    __syncthreads();
    if (wave / WPH == h) {
#pragma unroll
      for (int mt = 0; mt < MT; ++mt)
#pragma unroll
        for (int nt = 0; nt < NT; ++nt) {
          int ng = wave * NT * 16 + nt * 16 + l16;
          float bias = b2[ng];
          int nl = ng - h * CPH;
#pragma unroll
          for (int r = 0; r < 4; ++r)
            ybuf[nl * (BE + 1) + mt * 16 + quad * 4 + r] = acc[mt][nt][r] + bias;
        }
    }
    __syncthreads();
    {
      const int c = tid % CPH, g = tid / CPH;
      const int es = g * SL;
      float run = -INFINITY;
      int pd = sDst[es];
      for (int e = es; e < es + SL; ++e) {
        int d = sDst[e];
        if (d != pd) {
          atomicMax(&agg[(size_t)pd * D + h * CPH + c], enc_f32(run));
          run = -INFINITY;
          pd = d;
        }
        run = fmaxf(run, ybuf[c * (BE + 1) + e]);
      }
      atomicMax(&agg[(size_t)pd * D + h * CPH + c], enc_f32(run));
    }
  }
}

// MFMA MLP GEMM: Y = act(Xh @ W + b). Block: 64 rows x 128 cols; 4 waves,
// each wave 64x32 (MT=4, NT=2). Xh [M,K] f16; BT [NTOT,K] f16; fp32 acc.
template <int K, int NTOT, bool RELU, bool OUTF16>
__global__ __launch_bounds__(256) void mlp_mfma(
    const _Float16* __restrict__ Xh, const _Float16* __restrict__ BT,
    const float* __restrict__ bias, void* __restrict__ Yv) {
  constexpr int KT = 64;
  constexpr int SA = KT + 8;  // 72
  __shared__ __align__(16) _Float16 As[64 * SA];
  __shared__ __align__(16) _Float16 Bs[128 * SA];
  const int tid = threadIdx.x;
  const int wave = tid >> 6, lane = tid & 63;
  const int l16 = lane & 15, quad = lane >> 4;
  const int row0 = blockIdx.x * 64;
  const int cb0 = blockIdx.y * 128;
  f32x4 acc[4][2] = {};
  for (int k0 = 0; k0 < K; k0 += KT) {
    __syncthreads();
    for (int idx = tid; idx < 512; idx += 256) {
      int r = idx >> 3, cc = idx & 7;
      int rr = row0 + r; if (rr >= NNODES) rr = NNODES - 1;
      *(float4*)&As[r * SA + cc * 8] = *(const float4*)&Xh[(size_t)rr * K + k0 + cc * 8];
    }
    for (int idx = tid; idx < 1024; idx += 256) {
      int n = idx >> 3, cc = idx & 7;
      *(float4*)&Bs[n * SA + cc * 8] = *(const float4*)&BT[(size_t)(cb0 + n) * K + k0 + cc * 8];
    }
    __syncthreads();
#pragma unroll
    for (int kh = 0; kh < 2; ++kh) {
      f16x8 af[4], bf[2];
#pragma unroll
      for (int mt = 0; mt < 4; ++mt)
        af[mt] = *(const f16x8*)&As[(mt * 16 + l16) * SA + kh * 32 + quad * 8];
#pragma unroll
      for (int nt = 0; nt < 2; ++nt)
        bf[nt] = *(const f16x8*)&Bs[(wave * 32 + nt * 16 + l16) * SA + kh * 32 + quad * 8];
#pragma unroll
      for (int mt = 0; mt < 4; ++mt)
#pragma unroll
        for (int nt = 0; nt < 2; ++nt)
          acc[mt][nt] = __builtin_amdgcn_mfma_f32_16x16x32_f16(af[mt], bf[nt], acc[mt][nt], 0, 0, 0);
    }
  }
#pragma unroll
  for (int nt = 0; nt < 2; ++nt) {
    int n = cb0 + wave * 32 + nt * 16 + l16;
    float bv = bias[n];
#pragma unroll
    for (int mt = 0; mt < 4; ++mt) {
#pragma unroll
      for (int r = 0; r < 4; ++r) {
        int m = row0 + mt * 16 + quad * 4 + r;
        if (m < NNODES) {
          float v = acc[mt][nt][r] + bv;
          if (RELU) v = fmaxf(v, 0.0f);
          if (OUTF16) ((_Float16*)Yv)[(size_t)m * NTOT + n] = (_Float16)v;
          else ((float*)Yv)[(size_t)m * NTOT + n] = v;
        }
      }
    }
  }
}

// Final 256 -> 4 projection.
__global__ __launch_bounds__(256) void final_kernel(
    const float* __restrict__ X, const float* __restrict__ W,
    const float* __restrict__ b, float* __restrict__ out) {
  __shared__ float as[64][65];
  __shared__ float ws3[256][4];
  __shared__ float bs[4];
  const int tid = threadIdx.x;
  const int row0 = blockIdx.x * 64;
  for (int idx = tid; idx < 256 * 4; idx += 256) ws3[idx >> 2][idx & 3] = W[idx];
  if (tid < 4) bs[tid] = b[tid];
  const int r = tid >> 2, c = tid & 3;
  float acc = 0.0f;
  for (int k0 = 0; k0 < 256; k0 += 64) {
    __syncthreads();
    for (int idx = tid; idx < 64 * 64; idx += 256) {
      int r2 = idx >> 6, k = idx & 63;
      int rr = row0 + r2; if (rr >= NNODES) rr = NNODES - 1;
      as[r2][k] = X[(size_t)rr * 256 + k0 + k];
    }
    __syncthreads();
#pragma unroll
    for (int kk = 0; kk < 64; ++kk) acc = fmaf(as[r][kk], ws3[k0 + kk][c], acc);
  }
  int rr = row0 + r;
  if (rr < NNODES) out[(size_t)rr * 4 + c] = acc + bs[c];
}

extern "C" void kernel_launch(void* const* d_in, const int* in_sizes, int n_in,
                              void* d_out, int out_size, void* d_ws, size_t ws_size,
                              hipStream_t stream) {
  const float* x = (const float*)d_in[0];
  const int* eidx = (const int*)d_in[1];  // int32
  const float* w1a = (const float*)d_in[3];
  const float* b1a = (const float*)d_in[4];
  const float* w1b = (const float*)d_in[5];
  const float* b1b = (const float*)d_in[6];
  const float* w2a = (const float*)d_in[7];
  const float* b2a = (const float*)d_in[8];
  const float* w2b = (const float*)d_in[9];
  const float* b2b = (const float*)d_in[10];
  const float* w3a = (const float*)d_in[11];
  const float* b3a = (const float*)d_in[12];
  const float* w3b = (const float*)d_in[13];
  const float* b3b = (const float*)d_in[14];
  const float* wm1 = (const float*)d_in[15];
  const float* bm1 = (const float*)d_in[16];
  const float* wm2 = (const float*)d_in[17];
  const float* bm2 = (const float*)d_in[18];
  const float* wm3 = (const float*)d_in[19];
  const float* bm3 = (const float*)d_in[20];
  float* out = (float*)d_out;

  // Workspace (floats): hcat[N*448] | P[N*256] | Q[N*256] | agg[N*256] | sedge[E]
  // Overlays: deg/cur on agg (CSR build, pre-init); hcat_h (f16) on P after layer 3;
  // mh1h (f16) on Q; mh2 fp32 on agg; wm1h (f16) on hcat (after hcat->f16).
  // Edge fragment weights + wm2h live in d_out (434 KB < 480 KB).
  float* wsf = (float*)d_ws;
  float* hcat = wsf;
  float* P = wsf + (size_t)NNODES * 448;
  float* Q = P + (size_t)NNODES * 256;
  unsigned* agg = (unsigned*)(Q + (size_t)NNODES * 256);
  unsigned* sedge = agg + (size_t)NNODES * 256;
  int* deg = (int*)agg;
  int* cur = deg + NNODES;
  _Float16* hcat_h = (_Float16*)P;
  _Float16* mh1h = (_Float16*)Q;
  float* mh2 = (float*)agg;
  _Float16* wm1h = (_Float16*)hcat;
  _Float16* w1f = (_Float16*)d_out;        // 64*64   = 4096 halves
  _Float16* w2f = w1f + 4096;              // 128*128 = 16384
  _Float16* w3f = w2f + 16384;             // 256*256 = 65536
  _Float16* wm2h = w3f + 65536;            // 256*512 = 131072 -> total 434 KB

  const int ROWB64 = (NNODES + 63) / 64;     // 469
  const int EB = (NEDGES + 255) / 256;

  // ---- Build dst-sorted edge list (CSR order), reused by all 3 layers
  fill_u32<<<(NNODES + 255) / 256, 256, 0, stream>>>((unsigned*)deg, NNODES, 0u);
  hist_kernel<<<EB, 256, 0, stream>>>(eidx, deg);
  scan_kernel<<<1, 1024, 0, stream>>>(deg, cur);
  scatter_kernel<<<EB, 256, 0, stream>>>(eidx, cur, sedge);
  // ---- fragment-ordered f16 edge weights (into d_out scratch)
  cvt_bfrag<<<(64 * 64 + 255) / 256, 256, 0, stream>>>(w1b, w1f, 64);
  cvt_bfrag<<<(128 * 128 + 255) / 256, 256, 0, stream>>>(w2b, w2f, 128);
  cvt_bfrag<<<(256 * 256 + 255) / 256, 256, 0, stream>>>(w3b, w3f, 256);
  cvt_wT<<<(512 * 256 + 255) / 256, 256, 0, stream>>>(wm2, wm2h, 512, 256);

  // ---- EdgeConv 1: C=3 -> 64
  {
    int total = NNODES * 64;
    fill_u32<<<(total + 255) / 256, 256, 0, stream>>>(agg, total, ENC_NEGINF);
    pq_kernel<3, 64><<<dim3(ROWB64, 1), 256, 0, stream>>>(x, 3, 0, w1a, b1a, P, Q);
    edge_mfma<64><<<NEDGES / 64, 256, 0, stream>>>(sedge, P, Q, w1f, b1b, agg);
    decode_kernel<<<(total + 255) / 256, 256, 0, stream>>>(agg, hcat + 0, 6, total);
  }
  // ---- EdgeConv 2: C=64 -> 128
  {
    int total = NNODES * 128;
    fill_u32<<<(total + 255) / 256, 256, 0, stream>>>(agg, total, ENC_NEGINF);
    pq_kernel<64, 128><<<dim3(ROWB64, 2), 256, 0, stream>>>(hcat, 448, 0, w2a, b2a, P, Q);
    edge_mfma<128><<<NEDGES / 64, 256, 0, stream>>>(sedge, P, Q, w2f, b2b, agg);
    decode_kernel<<<(total + 255) / 256, 256, 0, stream>>>(agg, hcat + 64, 7, total);
  }
  // ---- EdgeConv 3: C=128 -> 256
  {
    int total = NNODES * 256;
    fill_u32<<<(total + 255) / 256, 256, 0, stream>>>(agg, total, ENC_NEGINF);
    pq_kernel<128, 256><<<dim3(ROWB64, 4), 256, 0, stream>>>(hcat, 448, 64, w3a, b3a, P, Q);
    edge_mfma<256><<<NEDGES / 64, 256, 0, stream>>>(sedge, P, Q, w3f, b3b, agg);
    decode_kernel<<<(total + 255) / 256, 256, 0, stream>>>(agg, hcat + 192, 8, total);
  }
  // ---- MLP head (MFMA f16)
  cvt_f16<<<(NNODES * 448 / 4 + 255) / 256, 256, 0, stream>>>(hcat, hcat_h, NNODES * 448 / 4);
  cvt_wT<<<(448 * 512 + 255) / 256, 256, 0, stream>>>(wm1, wm1h, 448, 512);  // hcat now dead
  mlp_mfma<448, 512, true, true><<<dim3(ROWB64, 4), 256, 0, stream>>>(hcat_h, wm1h, bm1, mh1h);
  mlp_mfma<512, 256, true, false><<<dim3(ROWB64, 2), 256, 0, stream>>>(mh1h, wm2h, bm2, mh2);
  final_kernel<<<ROWB64, 256, 0, stream>>>(mh2, wm3, bm3, out);
}

// Round 7
// 653.736 us; speedup vs baseline: 7.1440x; 1.0759x over previous
//
#include <hip/hip_runtime.h>
#include <cstdint>
#include <cstddef>
#include <math.h>

#define NNODES 30000
#define NEDGES 480000

typedef _Float16 f16x8 __attribute__((ext_vector_type(8)));
typedef float f32x4 __attribute__((ext_vector_type(4)));

constexpr unsigned ENC_NEGINF = 0x007FFFFFu;  // encode(-inf)

__device__ __forceinline__ unsigned enc_f32(float f) {
  unsigned u = __float_as_uint(f);
  return (u & 0x80000000u) ? ~u : (u | 0x80000000u);
}
__device__ __forceinline__ float dec_f32(unsigned e) {
  unsigned u = (e & 0x80000000u) ? (e ^ 0x80000000u) : ~e;
  return __uint_as_float(u);
}

__global__ void fill_u32(unsigned* __restrict__ p, int n, unsigned v) {
  int i = blockIdx.x * 256 + threadIdx.x;
  if (i < n) p[i] = v;
}

// ---- CSR build: histogram -> exclusive scan -> scatter (sorted by dst) ----
__global__ void hist_kernel(const int* __restrict__ eidx, int* __restrict__ deg) {
  int e = blockIdx.x * 256 + threadIdx.x;
  if (e < NEDGES) atomicAdd(&deg[eidx[NEDGES + e]], 1);
}

__global__ __launch_bounds__(1024) void scan_kernel(const int* __restrict__ deg,
                                                    int* __restrict__ cur) {
  __shared__ int part[1024];
  const int tid = threadIdx.x;
  constexpr int PER = 30;  // 1024*30 = 30720 >= 30000
  int loc[PER];
  int s = 0;
  const int base = tid * PER;
#pragma unroll
  for (int i = 0; i < PER; ++i) {
    int idx = base + i;
    int v = (idx < NNODES) ? deg[idx] : 0;
    loc[i] = s;
    s += v;
  }
  part[tid] = s;
  __syncthreads();
  for (int d = 1; d < 1024; d <<= 1) {
    int t = (tid >= d) ? part[tid - d] : 0;
    __syncthreads();
    part[tid] += t;
    __syncthreads();
  }
  const int excl = part[tid] - s;
#pragma unroll
  for (int i = 0; i < PER; ++i) {
    int idx = base + i;
    if (idx < NNODES) cur[idx] = excl + loc[i];
  }
}

// Pack (dst<<16)|src — both < 30000 < 65536.
__global__ void scatter_kernel(const int* __restrict__ eidx, int* __restrict__ cur,
                               unsigned* __restrict__ sedge) {
  int e = blockIdx.x * 256 + threadIdx.x;
  if (e < NEDGES) {
    int s = eidx[e], d = eidx[NEDGES + e];
    int pos = atomicAdd(&cur[d], 1);
    sedge[pos] = ((unsigned)d << 16) | (unsigned)s;
  }
}

// Transposed f16 weight: BT[n*K + k] = (f16) W[k*N + n]  (W is [K,N]) — MLP path.
__global__ void cvt_wT(const float* __restrict__ W, _Float16* __restrict__ BT,
                       int Kd, int Nd) {
  int idx = blockIdx.x * 256 + threadIdx.x;
  if (idx < Kd * Nd) {
    int k = idx / Nd, n = idx % Nd;  // coalesced read of W[k][n]
    BT[(size_t)n * Kd + k] = (_Float16)W[idx];
  }
}

// Edge weight -> MFMA-fragment order: Bf[((ks*NTILES + tile)*64 + lane)*8 + j]
// = W[k][n], n = tile*16 + (lane&15), k = ks*32 + (lane>>4)*8 + j.
__global__ void cvt_bfrag(const float* __restrict__ W, _Float16* __restrict__ Bf, int Dd) {
  int idx = blockIdx.x * 256 + threadIdx.x;
  if (idx >= Dd * Dd) return;
  int j = idx & 7;
  int lane = (idx >> 3) & 63;
  int rest = idx >> 9;  // ks*NTILES + tile
  int ntiles = Dd >> 4;
  int ks = rest / ntiles, tile = rest % ntiles;
  int n = tile * 16 + (lane & 15);
  int k = ks * 32 + (lane >> 4) * 8 + j;
  Bf[idx] = (_Float16)W[(size_t)k * Dd + n];
}

// fp32 -> f16 elementwise (n divisible by 4)
__global__ void cvt_f16(const float* __restrict__ X, _Float16* __restrict__ Y, int n4) {
  int i = blockIdx.x * 256 + threadIdx.x;
  if (i < n4) {
    float4 v = *(const float4*)&X[i * 4];
    union { _Float16 h[4]; float2 f2; } u;
    u.h[0] = (_Float16)v.x; u.h[1] = (_Float16)v.y;
    u.h[2] = (_Float16)v.z; u.h[3] = (_Float16)v.w;
    *(float2*)&Y[i * 4] = u.f2;
  }
}

// Decode encoded max-agg into hcat slice (hc already offset by column).
__global__ void decode_kernel(const unsigned* __restrict__ agg, float* __restrict__ hc,
                              int shift, int total) {
  int i = blockIdx.x * 256 + threadIdx.x;
  if (i < total) {
    unsigned e = agg[i];
    float v = (e == ENC_NEGINF) ? 0.0f : dec_f32(e);
    int r = i >> shift;
    int c = i & ((1 << shift) - 1);
    hc[(size_t)r * 448 + c] = v;
  }
}

// P[n] = x[n] @ (W1_top - W1_bot) + b1 ; Q[n] = x[n] @ W1_bot  (f16 outputs)
template <int K, int D>
__global__ __launch_bounds__(256) void pq_kernel(
    const float* __restrict__ X, int ldx, int koff,
    const float* __restrict__ W1, const float* __restrict__ b1,
    _Float16* __restrict__ P, _Float16* __restrict__ Q) {
  constexpr int KT = 16;
  __shared__ float xs[64][KT + 1];
  __shared__ float wt[KT][64];
  __shared__ float wb[KT][64];
  const int tid = threadIdx.x;
  const int row0 = blockIdx.x * 64;
  const int cb0 = blockIdx.y * 64;
  const int cg = tid & 15, rg = tid >> 4;
  const int c0 = cg * 4, r0 = rg * 4;
  float p[4][4] = {}, q[4][4] = {};
  for (int k0 = 0; k0 < K; k0 += KT) {
    const int kt = (K - k0 < KT) ? (K - k0) : KT;
    for (int idx = tid; idx < 64 * KT; idx += 256) {
      int k = idx & (KT - 1), r = idx >> 4;
      if (k < kt) {
        int rr = row0 + r; if (rr >= NNODES) rr = NNODES - 1;
        xs[r][k] = X[(size_t)rr * ldx + koff + k0 + k];
      }
    }
    for (int idx = tid; idx < KT * 64; idx += 256) {
      int k = idx >> 6, c = idx & 63;
      if (k < kt) {
        wt[k][c] = W1[(size_t)(k0 + k) * D + cb0 + c];
        wb[k][c] = W1[(size_t)(K + k0 + k) * D + cb0 + c];
      }
    }
    __syncthreads();
    for (int kk = 0; kk < kt; ++kk) {
      float xv[4];
#pragma unroll
      for (int i = 0; i < 4; ++i) xv[i] = xs[r0 + i][kk];
      const float4 wtv = *(const float4*)&wt[kk][c0];
      const float4 wbv = *(const float4*)&wb[kk][c0];
      float dv[4] = {wtv.x - wbv.x, wtv.y - wbv.y, wtv.z - wbv.z, wtv.w - wbv.w};
      float bv[4] = {wbv.x, wbv.y, wbv.z, wbv.w};
#pragma unroll
      for (int i = 0; i < 4; ++i) {
#pragma unroll
        for (int j = 0; j < 4; ++j) {
          p[i][j] = fmaf(xv[i], dv[j], p[i][j]);
          q[i][j] = fmaf(xv[i], bv[j], q[i][j]);
        }
      }
    }
    __syncthreads();
  }
  float b1v[4];
#pragma unroll
  for (int j = 0; j < 4; ++j) b1v[j] = b1[cb0 + c0 + j];
#pragma unroll
  for (int i = 0; i < 4; ++i) {
    int rr = row0 + r0 + i;
    if (rr < NNODES) {
      union { _Float16 h[4]; float2 f2; } up, uq;
#pragma unroll
      for (int j = 0; j < 4; ++j) {
        up.h[j] = (_Float16)(p[i][j] + b1v[j]);
        uq.h[j] = (_Float16)q[i][j];
      }
      *(float2*)&P[(size_t)rr * D + cb0 + c0] = up.f2;
      *(float2*)&Q[(size_t)rr * D + cb0 + c0] = uq.f2;
    }
  }
}

// MFMA edge kernel (dst-sorted edges): t1 = relu(Ph[dst]+Qh[src]) (f16 packed)
// -> f16 LDS; y = t1 @ W2, B fragments direct from global (fragment-ordered,
// L2-resident, no K-loop barriers); +b2; in-block segmented max; few atomics.
template <int D>
__global__ __launch_bounds__(256) void edge_mfma(
    const unsigned* __restrict__ sedge,
    const _Float16* __restrict__ P, const _Float16* __restrict__ Q,
    const _Float16* __restrict__ Bf,  // fragment-ordered f16 W2
    const float* __restrict__ b2,
    unsigned* __restrict__ agg) {
  constexpr int BE = 64;                 // edges per block
  constexpr int MT = 4;                  // M(edge)-tiles of 16
  constexpr int NT = D / 64;             // N-tiles per wave
  constexpr int NTILES = D / 16;
  constexpr int NSTEP = D / 32;          // K steps of 32
  constexpr int SA = D + 8;              // A stride in halves
  constexpr int HALVES = (D == 64) ? 1 : 2;
  constexpr int CPH = D / HALVES;        // cols per half in phase C
  constexpr int WPH = 4 / HALVES;        // waves per half
  constexpr int SL = BE * CPH / 256;     // edges per scan slice
  constexpr int ABYTES = BE * SA * 2;
  constexpr int YBYTES = CPH * (BE + 1) * 4;
  constexpr int SBYTES = (ABYTES > YBYTES) ? ABYTES : YBYTES;
  __shared__ __align__(16) char smem[SBYTES];
  __shared__ int sSrc[BE], sDst[BE];
  _Float16* Abuf = (_Float16*)smem;
  float* ybuf = (float*)smem;            // overlays A after GEMM

  const int tid = threadIdx.x;
  const int wave = tid >> 6, lane = tid & 63;
  const int l16 = lane & 15, quad = lane >> 4;
  const int ebase = blockIdx.x * BE;
  if (tid < BE) {
    unsigned pk = sedge[ebase + tid];
    sSrc[tid] = (int)(pk & 0xFFFFu);
    sDst[tid] = (int)(pk >> 16);
  }
  __syncthreads();
  // ---- Phase A: t1 = relu(P[dst]+Q[src]) in f16 into Abuf[e][k]
  {
    const int e = tid >> 2, qd = tid & 3;
    const _Float16* Pr = P + (size_t)sDst[e] * D;
    const _Float16* Qr = Q + (size_t)sSrc[e] * D;
#pragma unroll
    for (int t = 0; t < D / 32; ++t) {
      int k = (qd + 4 * t) * 8;
      f16x8 pv = *(const f16x8*)(Pr + k);
      f16x8 qv = *(const f16x8*)(Qr + k);
      f16x8 s = pv + qv;
#pragma unroll
      for (int j = 0; j < 8; ++j) s[j] = (s[j] > (_Float16)0) ? s[j] : (_Float16)0;
      *(f16x8*)&Abuf[e * SA + k] = s;
    }
  }
  __syncthreads();
  // ---- Phase B: GEMM, B fragments direct from global (no barriers)
  f32x4 acc[MT][NT] = {};
  const _Float16* BfW = Bf + ((size_t)(wave * NT) * 64 + lane) * 8;
#pragma unroll
  for (int ks = 0; ks < NSTEP; ++ks) {
    f16x8 bf[NT], af[MT];
#pragma unroll
    for (int nt = 0; nt < NT; ++nt)
      bf[nt] = *(const f16x8*)(BfW + ((size_t)ks * NTILES + nt) * 64 * 8);
#pragma unroll
    for (int mt = 0; mt < MT; ++mt)
      af[mt] = *(const f16x8*)&Abuf[(mt * 16 + l16) * SA + ks * 32 + quad * 8];
#pragma unroll
    for (int mt = 0; mt < MT; ++mt)
#pragma unroll
      for (int nt = 0; nt < NT; ++nt)
        acc[mt][nt] = __builtin_amdgcn_mfma_f32_16x16x32_f16(af[mt], bf[nt], acc[mt][nt], 0, 0, 0);
  }
  // ---- Phase C: +bias, segmented max over sorted dst, atomics
  for (int h = 0; h < HALVES; ++h) {
    __syncthreads();
    if (wave / WPH == h) {
#pragma unroll
      for (int mt = 0; mt < MT; ++mt)
#pragma unroll
        for (int nt = 0; nt < NT; ++nt) {
          int ng = wave * NT * 16 + nt * 16 + l16;
          float bias = b2[ng];
          int nl = ng - h * CPH;
#pragma unroll
          for (int r = 0; r < 4; ++r)
            ybuf[nl * (BE + 1) + mt * 16 + quad * 4 + r] = acc[mt][nt][r] + bias;
        }
    }
    __syncthreads();
    {
      const int c = tid % CPH, g = tid / CPH;
      const int es = g * SL;
      float run = -INFINITY;
      int pd = sDst[es];
      for (int e = es; e < es + SL; ++e) {
        int d = sDst[e];
        if (d != pd) {
          atomicMax(&agg[(size_t)pd * D + h * CPH + c], enc_f32(run));
          run = -INFINITY;
          pd = d;
        }
        run = fmaxf(run, ybuf[c * (BE + 1) + e]);
      }
      atomicMax(&agg[(size_t)pd * D + h * CPH + c], enc_f32(run));
    }
  }
}

// MFMA MLP GEMM: Y = act(Xh @ W + b). Block: 64 rows x 128 cols; 4 waves,
// each wave 64x32 (MT=4, NT=2). Xh [M,K] f16; BT [NTOT,K] f16; fp32 acc.
template <int K, int NTOT, bool RELU, bool OUTF16>
__global__ __launch_bounds__(256) void mlp_mfma(
    const _Float16* __restrict__ Xh, const _Float16* __restrict__ BT,
    const float* __restrict__ bias, void* __restrict__ Yv) {
  constexpr int KT = 64;
  constexpr int SA = KT + 8;  // 72
  __shared__ __align__(16) _Float16 As[64 * SA];
  __shared__ __align__(16) _Float16 Bs[128 * SA];
  const int tid = threadIdx.x;
  const int wave = tid >> 6, lane = tid & 63;
  const int l16 = lane & 15, quad = lane >> 4;
  const int row0 = blockIdx.x * 64;
  const int cb0 = blockIdx.y * 128;
  f32x4 acc[4][2] = {};
  for (int k0 = 0; k0 < K; k0 += KT) {
    __syncthreads();
    for (int idx = tid; idx < 512; idx += 256) {
      int r = idx >> 3, cc = idx & 7;
      int rr = row0 + r; if (rr >= NNODES) rr = NNODES - 1;
      *(float4*)&As[r * SA + cc * 8] = *(const float4*)&Xh[(size_t)rr * K + k0 + cc * 8];
    }
    for (int idx = tid; idx < 1024; idx += 256) {
      int n = idx >> 3, cc = idx & 7;
      *(float4*)&Bs[n * SA + cc * 8] = *(const float4*)&BT[(size_t)(cb0 + n) * K + k0 + cc * 8];
    }
    __syncthreads();
#pragma unroll
    for (int kh = 0; kh < 2; ++kh) {
      f16x8 af[4], bf[2];
#pragma unroll
      for (int mt = 0; mt < 4; ++mt)
        af[mt] = *(const f16x8*)&As[(mt * 16 + l16) * SA + kh * 32 + quad * 8];
#pragma unroll
      for (int nt = 0; nt < 2; ++nt)
        bf[nt] = *(const f16x8*)&Bs[(wave * 32 + nt * 16 + l16) * SA + kh * 32 + quad * 8];
#pragma unroll
      for (int mt = 0; mt < 4; ++mt)
#pragma unroll
        for (int nt = 0; nt < 2; ++nt)
          acc[mt][nt] = __builtin_amdgcn_mfma_f32_16x16x32_f16(af[mt], bf[nt], acc[mt][nt], 0, 0, 0);
    }
  }
#pragma unroll
  for (int nt = 0; nt < 2; ++nt) {
    int n = cb0 + wave * 32 + nt * 16 + l16;
    float bv = bias[n];
#pragma unroll
    for (int mt = 0; mt < 4; ++mt) {
#pragma unroll
      for (int r = 0; r < 4; ++r) {
        int m = row0 + mt * 16 + quad * 4 + r;
        if (m < NNODES) {
          float v = acc[mt][nt][r] + bv;
          if (RELU) v = fmaxf(v, 0.0f);
          if (OUTF16) ((_Float16*)Yv)[(size_t)m * NTOT + n] = (_Float16)v;
          else ((float*)Yv)[(size_t)m * NTOT + n] = v;
        }
      }
    }
  }
}

// Final 256 -> 4 projection.
__global__ __launch_bounds__(256) void final_kernel(
    const float* __restrict__ X, const float* __restrict__ W,
    const float* __restrict__ b, float* __restrict__ out) {
  __shared__ float as[64][65];
  __shared__ float ws3[256][4];
  __shared__ float bs[4];
  const int tid = threadIdx.x;
  const int row0 = blockIdx.x * 64;
  for (int idx = tid; idx < 256 * 4; idx += 256) ws3[idx >> 2][idx & 3] = W[idx];
  if (tid < 4) bs[tid] = b[tid];
  const int r = tid >> 2, c = tid & 3;
  float acc = 0.0f;
  for (int k0 = 0; k0 < 256; k0 += 64) {
    __syncthreads();
    for (int idx = tid; idx < 64 * 64; idx += 256) {
      int r2 = idx >> 6, k = idx & 63;
      int rr = row0 + r2; if (rr >= NNODES) rr = NNODES - 1;
      as[r2][k] = X[(size_t)rr * 256 + k0 + k];
    }
    __syncthreads();
#pragma unroll
    for (int kk = 0; kk < 64; ++kk) acc = fmaf(as[r][kk], ws3[k0 + kk][c], acc);
  }
  int rr = row0 + r;
  if (rr < NNODES) out[(size_t)rr * 4 + c] = acc + bs[c];
}

extern "C" void kernel_launch(void* const* d_in, const int* in_sizes, int n_in,
                              void* d_out, int out_size, void* d_ws, size_t ws_size,
                              hipStream_t stream) {
  const float* x = (const float*)d_in[0];
  const int* eidx = (const int*)d_in[1];  // int32
  const float* w1a = (const float*)d_in[3];
  const float* b1a = (const float*)d_in[4];
  const float* w1b = (const float*)d_in[5];
  const float* b1b = (const float*)d_in[6];
  const float* w2a = (const float*)d_in[7];
  const float* b2a = (const float*)d_in[8];
  const float* w2b = (const float*)d_in[9];
  const float* b2b = (const float*)d_in[10];
  const float* w3a = (const float*)d_in[11];
  const float* b3a = (const float*)d_in[12];
  const float* w3b = (const float*)d_in[13];
  const float* b3b = (const float*)d_in[14];
  const float* wm1 = (const float*)d_in[15];
  const float* bm1 = (const float*)d_in[16];
  const float* wm2 = (const float*)d_in[17];
  const float* bm2 = (const float*)d_in[18];
  const float* wm3 = (const float*)d_in[19];
  const float* bm3 = (const float*)d_in[20];
  float* out = (float*)d_out;

  // Workspace (floats): hcat[N*448] | Ph[N*256 h] | Qh[N*256 h] | agg[N*256 u32] | sedge[E]
  // Overlays: deg/cur on agg (CSR build, pre-agg-init); hcat_h (f16, N*448 h) on agg
  // after layer-3 decode; mh1h (f16, N*512 h) on Ph+Qh; wm1h on hcat start;
  // mh2 (fp32, N*256) on hcat+131072. Edge frag weights + wm2h in d_out (434 KB).
  float* wsf = (float*)d_ws;
  float* hcat = wsf;
  _Float16* Ph = (_Float16*)(wsf + (size_t)NNODES * 448);
  _Float16* Qh = Ph + (size_t)NNODES * 256;
  unsigned* agg = (unsigned*)(Qh + (size_t)NNODES * 256);
  unsigned* sedge = agg + (size_t)NNODES * 256;
  int* deg = (int*)agg;
  int* cur = deg + NNODES;
  _Float16* hcat_h = (_Float16*)agg;
  _Float16* mh1h = Ph;
  _Float16* wm1h = (_Float16*)hcat;
  float* mh2 = hcat + 131072;
  _Float16* w1f = (_Float16*)d_out;        // 64*64   = 4096 halves
  _Float16* w2f = w1f + 4096;              // 128*128 = 16384
  _Float16* w3f = w2f + 16384;             // 256*256 = 65536
  _Float16* wm2h = w3f + 65536;            // 256*512 = 131072 -> total 434 KB

  const int ROWB64 = (NNODES + 63) / 64;     // 469
  const int EB = (NEDGES + 255) / 256;

  // ---- Build dst-sorted edge list (CSR order), reused by all 3 layers
  fill_u32<<<(NNODES + 255) / 256, 256, 0, stream>>>((unsigned*)deg, NNODES, 0u);
  hist_kernel<<<EB, 256, 0, stream>>>(eidx, deg);
  scan_kernel<<<1, 1024, 0, stream>>>(deg, cur);
  scatter_kernel<<<EB, 256, 0, stream>>>(eidx, cur, sedge);
  // ---- fragment-ordered f16 edge weights (into d_out scratch)
  cvt_bfrag<<<(64 * 64 + 255) / 256, 256, 0, stream>>>(w1b, w1f, 64);
  cvt_bfrag<<<(128 * 128 + 255) / 256, 256, 0, stream>>>(w2b, w2f, 128);
  cvt_bfrag<<<(256 * 256 + 255) / 256, 256, 0, stream>>>(w3b, w3f, 256);
  cvt_wT<<<(512 * 256 + 255) / 256, 256, 0, stream>>>(wm2, wm2h, 512, 256);

  // ---- EdgeConv 1: C=3 -> 64
  {
    int total = NNODES * 64;
    fill_u32<<<(total + 255) / 256, 256, 0, stream>>>(agg, total, ENC_NEGINF);
    pq_kernel<3, 64><<<dim3(ROWB64, 1), 256, 0, stream>>>(x, 3, 0, w1a, b1a, Ph, Qh);
    edge_mfma<64><<<NEDGES / 64, 256, 0, stream>>>(sedge, Ph, Qh, w1f, b1b, agg);
    decode_kernel<<<(total + 255) / 256, 256, 0, stream>>>(agg, hcat + 0, 6, total);
  }
  // ---- EdgeConv 2: C=64 -> 128
  {
    int total = NNODES * 128;
    fill_u32<<<(total + 255) / 256, 256, 0, stream>>>(agg, total, ENC_NEGINF);
    pq_kernel<64, 128><<<dim3(ROWB64, 2), 256, 0, stream>>>(hcat, 448, 0, w2a, b2a, Ph, Qh);
    edge_mfma<128><<<NEDGES / 64, 256, 0, stream>>>(sedge, Ph, Qh, w2f, b2b, agg);
    decode_kernel<<<(total + 255) / 256, 256, 0, stream>>>(agg, hcat + 64, 7, total);
  }
  // ---- EdgeConv 3: C=128 -> 256
  {
    int total = NNODES * 256;
    fill_u32<<<(total + 255) / 256, 256, 0, stream>>>(agg, total, ENC_NEGINF);
    pq_kernel<128, 256><<<dim3(ROWB64, 4), 256, 0, stream>>>(hcat, 448, 64, w3a, b3a, Ph, Qh);
    edge_mfma<256><<<NEDGES / 64, 256, 0, stream>>>(sedge, Ph, Qh, w3f, b3b, agg);
    decode_kernel<<<(total + 255) / 256, 256, 0, stream>>>(agg, hcat + 192, 8, total);
  }
  // ---- MLP head (MFMA f16)
  cvt_f16<<<(NNODES * 448 / 4 + 255) / 256, 256, 0, stream>>>(hcat, hcat_h, NNODES * 448 / 4);
  cvt_wT<<<(448 * 512 + 255) / 256, 256, 0, stream>>>(wm1, wm1h, 448, 512);  // hcat now dead
  mlp_mfma<448, 512, true, true><<<dim3(ROWB64, 4), 256, 0, stream>>>(hcat_h, wm1h, bm1, mh1h);
  mlp_mfma<512, 256, true, false><<<dim3(ROWB64, 2), 256, 0, stream>>>(mh1h, wm2h, bm2, mh2);
  final_kernel<<<ROWB64, 256, 0, stream>>>(mh2, wm3, bm3, out);
}

// Round 8
// 575.582 us; speedup vs baseline: 8.1140x; 1.1358x over previous
//
#include <hip/hip_runtime.h>
#include <cstdint>
#include <cstddef>
#include <math.h>

#define NNODES 30000
#define NEDGES 480000

typedef _Float16 f16x8 __attribute__((ext_vector_type(8)));
typedef float f32x4 __attribute__((ext_vector_type(4)));

constexpr unsigned ENC_NEGINF = 0x007FFFFFu;  // encode(-inf)

__device__ __forceinline__ unsigned enc_f32(float f) {
  unsigned u = __float_as_uint(f);
  return (u & 0x80000000u) ? ~u : (u | 0x80000000u);
}
__device__ __forceinline__ float dec_f32(unsigned e) {
  unsigned u = (e & 0x80000000u) ? (e ^ 0x80000000u) : ~e;
  return __uint_as_float(u);
}

__global__ void fill_u32(unsigned* __restrict__ p, int n, unsigned v) {
  int i = blockIdx.x * 256 + threadIdx.x;
  if (i < n) p[i] = v;
}

// ---- CSR build: histogram -> exclusive scan -> scatter (sorted by dst) ----
__global__ void hist_kernel(const int* __restrict__ eidx, int* __restrict__ deg) {
  int e = blockIdx.x * 256 + threadIdx.x;
  if (e < NEDGES) atomicAdd(&deg[eidx[NEDGES + e]], 1);
}

__global__ __launch_bounds__(1024) void scan_kernel(const int* __restrict__ deg,
                                                    int* __restrict__ cur) {
  __shared__ int part[1024];
  const int tid = threadIdx.x;
  constexpr int PER = 30;  // 1024*30 = 30720 >= 30000
  int loc[PER];
  int s = 0;
  const int base = tid * PER;
#pragma unroll
  for (int i = 0; i < PER; ++i) {
    int idx = base + i;
    int v = (idx < NNODES) ? deg[idx] : 0;
    loc[i] = s;
    s += v;
  }
  part[tid] = s;
  __syncthreads();
  for (int d = 1; d < 1024; d <<= 1) {
    int t = (tid >= d) ? part[tid - d] : 0;
    __syncthreads();
    part[tid] += t;
    __syncthreads();
  }
  const int excl = part[tid] - s;
#pragma unroll
  for (int i = 0; i < PER; ++i) {
    int idx = base + i;
    if (idx < NNODES) cur[idx] = excl + loc[i];
  }
}

// Pack (dst<<16)|src — both < 30000 < 65536.
__global__ void scatter_kernel(const int* __restrict__ eidx, int* __restrict__ cur,
                               unsigned* __restrict__ sedge) {
  int e = blockIdx.x * 256 + threadIdx.x;
  if (e < NEDGES) {
    int s = eidx[e], d = eidx[NEDGES + e];
    int pos = atomicAdd(&cur[d], 1);
    sedge[pos] = ((unsigned)d << 16) | (unsigned)s;
  }
}

// Transposed f16 weight: BT[n*K + k] = (f16) W[k*N + n]  (W is [K,N]) — MLP path.
__global__ void cvt_wT(const float* __restrict__ W, _Float16* __restrict__ BT,
                       int Kd, int Nd) {
  int idx = blockIdx.x * 256 + threadIdx.x;
  if (idx < Kd * Nd) {
    int k = idx / Nd, n = idx % Nd;  // coalesced read of W[k][n]
    BT[(size_t)n * Kd + k] = (_Float16)W[idx];
  }
}

// Edge weight -> MFMA-fragment order: Bf[((ks*NTILES + tile)*64 + lane)*8 + j]
// = W[k][n], n = tile*16 + (lane&15), k = ks*32 + (lane>>4)*8 + j.  (square Dd)
__global__ void cvt_bfrag(const float* __restrict__ W, _Float16* __restrict__ Bf, int Dd) {
  int idx = blockIdx.x * 256 + threadIdx.x;
  if (idx >= Dd * Dd) return;
  int j = idx & 7;
  int lane = (idx >> 3) & 63;
  int rest = idx >> 9;  // ks*NTILES + tile
  int ntiles = Dd >> 4;
  int ks = rest / ntiles, tile = rest % ntiles;
  int n = tile * 16 + (lane & 15);
  int k = ks * 32 + (lane >> 4) * 8 + j;
  Bf[idx] = (_Float16)W[(size_t)k * Dd + n];
}

// pq weights -> fragment order, two outputs: diff = top - bot, and bot.
// W1 is [2K, D]; fragment index over K x D.
__global__ void cvt_pqfrag(const float* __restrict__ W1, _Float16* __restrict__ Bfd,
                           _Float16* __restrict__ Bfb, int Kd, int Dd) {
  int idx = blockIdx.x * 256 + threadIdx.x;
  if (idx >= Kd * Dd) return;
  int j = idx & 7;
  int lane = (idx >> 3) & 63;
  int rest = idx >> 9;
  int ntiles = Dd >> 4;
  int ks = rest / ntiles, tile = rest % ntiles;
  int n = tile * 16 + (lane & 15);
  int k = ks * 32 + (lane >> 4) * 8 + j;
  float top = W1[(size_t)k * Dd + n];
  float bot = W1[(size_t)(Kd + k) * Dd + n];
  Bfd[idx] = (_Float16)(top - bot);
  Bfb[idx] = (_Float16)bot;
}

// Decode encoded max-agg into f16 hcat slice (hc already offset by column).
__global__ void decode_kernel(const unsigned* __restrict__ agg, _Float16* __restrict__ hc,
                              int shift, int total) {
  int i = blockIdx.x * 256 + threadIdx.x;
  if (i < total) {
    unsigned e = agg[i];
    float v = (e == ENC_NEGINF) ? 0.0f : dec_f32(e);
    int r = i >> shift;
    int c = i & ((1 << shift) - 1);
    hc[(size_t)r * 448 + c] = (_Float16)v;
  }
}

// Layer-1 P/Q (K=3, fp32 VALU — tiny): P = x@(Wt-Wb)+b1, Q = x@Wb, f16 out.
template <int K, int D>
__global__ __launch_bounds__(256) void pq_kernel(
    const float* __restrict__ X, int ldx,
    const float* __restrict__ W1, const float* __restrict__ b1,
    _Float16* __restrict__ P, _Float16* __restrict__ Q) {
  constexpr int KT = 16;
  __shared__ float xs[64][KT + 1];
  __shared__ float wt[KT][64];
  __shared__ float wb[KT][64];
  const int tid = threadIdx.x;
  const int row0 = blockIdx.x * 64;
  const int cb0 = blockIdx.y * 64;
  const int cg = tid & 15, rg = tid >> 4;
  const int c0 = cg * 4, r0 = rg * 4;
  float p[4][4] = {}, q[4][4] = {};
  for (int k0 = 0; k0 < K; k0 += KT) {
    const int kt = (K - k0 < KT) ? (K - k0) : KT;
    for (int idx = tid; idx < 64 * KT; idx += 256) {
      int k = idx & (KT - 1), r = idx >> 4;
      if (k < kt) {
        int rr = row0 + r; if (rr >= NNODES) rr = NNODES - 1;
        xs[r][k] = X[(size_t)rr * ldx + k0 + k];
      }
    }
    for (int idx = tid; idx < KT * 64; idx += 256) {
      int k = idx >> 6, c = idx & 63;
      if (k < kt) {
        wt[k][c] = W1[(size_t)(k0 + k) * D + cb0 + c];
        wb[k][c] = W1[(size_t)(K + k0 + k) * D + cb0 + c];
      }
    }
    __syncthreads();
    for (int kk = 0; kk < kt; ++kk) {
      float xv[4];
#pragma unroll
      for (int i = 0; i < 4; ++i) xv[i] = xs[r0 + i][kk];
      const float4 wtv = *(const float4*)&wt[kk][c0];
      const float4 wbv = *(const float4*)&wb[kk][c0];
      float dv[4] = {wtv.x - wbv.x, wtv.y - wbv.y, wtv.z - wbv.z, wtv.w - wbv.w};
      float bv[4] = {wbv.x, wbv.y, wbv.z, wbv.w};
#pragma unroll
      for (int i = 0; i < 4; ++i) {
#pragma unroll
        for (int j = 0; j < 4; ++j) {
          p[i][j] = fmaf(xv[i], dv[j], p[i][j]);
          q[i][j] = fmaf(xv[i], bv[j], q[i][j]);
        }
      }
    }
    __syncthreads();
  }
  float b1v[4];
#pragma unroll
  for (int j = 0; j < 4; ++j) b1v[j] = b1[cb0 + c0 + j];
#pragma unroll
  for (int i = 0; i < 4; ++i) {
    int rr = row0 + r0 + i;
    if (rr < NNODES) {
      union { _Float16 h[4]; float2 f2; } up, uq;
#pragma unroll
      for (int j = 0; j < 4; ++j) {
        up.h[j] = (_Float16)(p[i][j] + b1v[j]);
        uq.h[j] = (_Float16)q[i][j];
      }
      *(float2*)&P[(size_t)rr * D + cb0 + c0] = up.f2;
      *(float2*)&Q[(size_t)rr * D + cb0 + c0] = uq.f2;
    }
  }
}

// MFMA P/Q for layers 2/3: reads f16 hcat (ld 448, col offset koff), dual
// accumulators share A fragments; B fragments (diff & bot) direct from L2.
// Block: 64 rows x 128 cols (4 waves x 32 cols).
template <int K, int D>
__global__ __launch_bounds__(256) void pq_mfma(
    const _Float16* __restrict__ Xh, int koff,
    const _Float16* __restrict__ Bfd, const _Float16* __restrict__ Bfb,
    const float* __restrict__ b1,
    _Float16* __restrict__ P, _Float16* __restrict__ Q) {
  constexpr int SA = K + 8;
  constexpr int NSTEP = K / 32;
  constexpr int NTILES = D / 16;
  constexpr int CH = K / 8;
  __shared__ __align__(16) _Float16 As[64 * SA];
  const int tid = threadIdx.x;
  const int wave = tid >> 6, lane = tid & 63;
  const int l16 = lane & 15, quad = lane >> 4;
  const int row0 = blockIdx.x * 64;
  const int cb0 = blockIdx.y * 128;
  for (int idx = tid; idx < 64 * CH; idx += 256) {
    int r = idx / CH, cc = idx % CH;
    int rr = row0 + r; if (rr >= NNODES) rr = NNODES - 1;
    *(f16x8*)&As[r * SA + cc * 8] = *(const f16x8*)&Xh[(size_t)rr * 448 + koff + cc * 8];
  }
  __syncthreads();
  f32x4 accP[4][2] = {}, accQ[4][2] = {};
  const int tbase = cb0 / 16 + wave * 2;
#pragma unroll
  for (int ks = 0; ks < NSTEP; ++ks) {
    f16x8 af[4], bd[2], bb[2];
#pragma unroll
    for (int nt = 0; nt < 2; ++nt) {
      size_t off = (((size_t)ks * NTILES + tbase + nt) * 64 + lane) * 8;
      bd[nt] = *(const f16x8*)(Bfd + off);
      bb[nt] = *(const f16x8*)(Bfb + off);
    }
#pragma unroll
    for (int mt = 0; mt < 4; ++mt)
      af[mt] = *(const f16x8*)&As[(mt * 16 + l16) * SA + ks * 32 + quad * 8];
#pragma unroll
    for (int mt = 0; mt < 4; ++mt)
#pragma unroll
      for (int nt = 0; nt < 2; ++nt) {
        accP[mt][nt] = __builtin_amdgcn_mfma_f32_16x16x32_f16(af[mt], bd[nt], accP[mt][nt], 0, 0, 0);
        accQ[mt][nt] = __builtin_amdgcn_mfma_f32_16x16x32_f16(af[mt], bb[nt], accQ[mt][nt], 0, 0, 0);
      }
  }
#pragma unroll
  for (int nt = 0; nt < 2; ++nt) {
    int n = cb0 + wave * 32 + nt * 16 + l16;
    float bv = b1[n];
#pragma unroll
    for (int mt = 0; mt < 4; ++mt) {
#pragma unroll
      for (int r = 0; r < 4; ++r) {
        int m = row0 + mt * 16 + quad * 4 + r;
        if (m < NNODES) {
          P[(size_t)m * D + n] = (_Float16)(accP[mt][nt][r] + bv);
          Q[(size_t)m * D + n] = (_Float16)accQ[mt][nt][r];
        }
      }
    }
  }
}

// MFMA edge kernel (dst-sorted edges): t1 = relu(Ph[dst]+Qh[src]) (f16 packed)
// -> f16 LDS; y = t1 @ W2, B fragments direct from global; +b2; in-block
// segmented max; few atomics.
template <int D>
__global__ __launch_bounds__(256) void edge_mfma(
    const unsigned* __restrict__ sedge,
    const _Float16* __restrict__ P, const _Float16* __restrict__ Q,
    const _Float16* __restrict__ Bf,  // fragment-ordered f16 W2
    const float* __restrict__ b2,
    unsigned* __restrict__ agg) {
  constexpr int BE = 64;                 // edges per block
  constexpr int MT = 4;                  // M(edge)-tiles of 16
  constexpr int NT = D / 64;             // N-tiles per wave
  constexpr int NTILES = D / 16;
  constexpr int NSTEP = D / 32;          // K steps of 32
  constexpr int SA = D + 8;              // A stride in halves
  constexpr int HALVES = (D == 64) ? 1 : 2;
  constexpr int CPH = D / HALVES;        // cols per half in phase C
  constexpr int WPH = 4 / HALVES;        // waves per half
  constexpr int SL = BE * CPH / 256;     // edges per scan slice
  constexpr int ABYTES = BE * SA * 2;
  constexpr int YBYTES = CPH * (BE + 1) * 4;
  constexpr int SBYTES = (ABYTES > YBYTES) ? ABYTES : YBYTES;
  __shared__ __align__(16) char smem[SBYTES];
  __shared__ int sSrc[BE], sDst[BE];
  _Float16* Abuf = (_Float16*)smem;
  float* ybuf = (float*)smem;            // overlays A after GEMM

  const int tid = threadIdx.x;
  const int wave = tid >> 6, lane = tid & 63;
  const int l16 = lane & 15, quad = lane >> 4;
  const int ebase = blockIdx.x * BE;
  if (tid < BE) {
    unsigned pk = sedge[ebase + tid];
    sSrc[tid] = (int)(pk & 0xFFFFu);
    sDst[tid] = (int)(pk >> 16);
  }
  __syncthreads();
  // ---- Phase A: t1 = relu(P[dst]+Q[src]) in f16 into Abuf[e][k]
  {
    const int e = tid >> 2, qd = tid & 3;
    const _Float16* Pr = P + (size_t)sDst[e] * D;
    const _Float16* Qr = Q + (size_t)sSrc[e] * D;
#pragma unroll
    for (int t = 0; t < D / 32; ++t) {
      int k = (qd + 4 * t) * 8;
      f16x8 pv = *(const f16x8*)(Pr + k);
      f16x8 qv = *(const f16x8*)(Qr + k);
      f16x8 s = pv + qv;
#pragma unroll
      for (int j = 0; j < 8; ++j) s[j] = (s[j] > (_Float16)0) ? s[j] : (_Float16)0;
      *(f16x8*)&Abuf[e * SA + k] = s;
    }
  }
  __syncthreads();
  // ---- Phase B: GEMM, B fragments direct from global (no barriers)
  f32x4 acc[MT][NT] = {};
  const _Float16* BfW = Bf + ((size_t)(wave * NT) * 64 + lane) * 8;
#pragma unroll
  for (int ks = 0; ks < NSTEP; ++ks) {
    f16x8 bf[NT], af[MT];
#pragma unroll
    for (int nt = 0; nt < NT; ++nt)
      bf[nt] = *(const f16x8*)(BfW + ((size_t)ks * NTILES + nt) * 64 * 8);
#pragma unroll
    for (int mt = 0; mt < MT; ++mt)
      af[mt] = *(const f16x8*)&Abuf[(mt * 16 + l16) * SA + ks * 32 + quad * 8];
#pragma unroll
    for (int mt = 0; mt < MT; ++mt)
#pragma unroll
      for (int nt = 0; nt < NT; ++nt)
        acc[mt][nt] = __builtin_amdgcn_mfma_f32_16x16x32_f16(af[mt], bf[nt], acc[mt][nt], 0, 0, 0);
  }
  // ---- Phase C: +bias, segmented max over sorted dst, atomics
  for (int h = 0; h < HALVES; ++h) {
    __syncthreads();
    if (wave / WPH == h) {
#pragma unroll
      for (int mt = 0; mt < MT; ++mt)
#pragma unroll
        for (int nt = 0; nt < NT; ++nt) {
          int ng = wave * NT * 16 + nt * 16 + l16;
          float bias = b2[ng];
          int nl = ng - h * CPH;
#pragma unroll
          for (int r = 0; r < 4; ++r)
            ybuf[nl * (BE + 1) + mt * 16 + quad * 4 + r] = acc[mt][nt][r] + bias;
        }
    }
    __syncthreads();
    {
      const int c = tid % CPH, g = tid / CPH;
      const int es = g * SL;
      float run = -INFINITY;
      int pd = sDst[es];
      for (int e = es; e < es + SL; ++e) {
        int d = sDst[e];
        if (d != pd) {
          atomicMax(&agg[(size_t)pd * D + h * CPH + c], enc_f32(run));
          run = -INFINITY;
          pd = d;
        }
        run = fmaxf(run, ybuf[c * (BE + 1) + e]);
      }
      atomicMax(&agg[(size_t)pd * D + h * CPH + c], enc_f32(run));
    }
  }
}

// MFMA MLP GEMM: Y = act(Xh @ W + b). Block: 64 rows x 128 cols; 4 waves,
// each wave 64x32 (MT=4, NT=2). Xh [M,K] f16 (ld=K); BT [NTOT,K] f16; fp32 acc.
template <int K, int NTOT, bool RELU, bool OUTF16>
__global__ __launch_bounds__(256) void mlp_mfma(
    const _Float16* __restrict__ Xh, const _Float16* __restrict__ BT,
    const float* __restrict__ bias, void* __restrict__ Yv) {
  constexpr int KT = 64;
  constexpr int SA = KT + 8;  // 72
  __shared__ __align__(16) _Float16 As[64 * SA];
  __shared__ __align__(16) _Float16 Bs[128 * SA];
  const int tid = threadIdx.x;
  const int wave = tid >> 6, lane = tid & 63;
  const int l16 = lane & 15, quad = lane >> 4;
  const int row0 = blockIdx.x * 64;
  const int cb0 = blockIdx.y * 128;
  f32x4 acc[4][2] = {};
  for (int k0 = 0; k0 < K; k0 += KT) {
    __syncthreads();
    for (int idx = tid; idx < 512; idx += 256) {
      int r = idx >> 3, cc = idx & 7;
      int rr = row0 + r; if (rr >= NNODES) rr = NNODES - 1;
      *(float4*)&As[r * SA + cc * 8] = *(const float4*)&Xh[(size_t)rr * K + k0 + cc * 8];
    }
    for (int idx = tid; idx < 1024; idx += 256) {
      int n = idx >> 3, cc = idx & 7;
      *(float4*)&Bs[n * SA + cc * 8] = *(const float4*)&BT[(size_t)(cb0 + n) * K + k0 + cc * 8];
    }
    __syncthreads();
#pragma unroll
    for (int kh = 0; kh < 2; ++kh) {
      f16x8 af[4], bf[2];
#pragma unroll
      for (int mt = 0; mt < 4; ++mt)
        af[mt] = *(const f16x8*)&As[(mt * 16 + l16) * SA + kh * 32 + quad * 8];
#pragma unroll
      for (int nt = 0; nt < 2; ++nt)
        bf[nt] = *(const f16x8*)&Bs[(wave * 32 + nt * 16 + l16) * SA + kh * 32 + quad * 8];
#pragma unroll
      for (int mt = 0; mt < 4; ++mt)
#pragma unroll
        for (int nt = 0; nt < 2; ++nt)
          acc[mt][nt] = __builtin_amdgcn_mfma_f32_16x16x32_f16(af[mt], bf[nt], acc[mt][nt], 0, 0, 0);
    }
  }
#pragma unroll
  for (int nt = 0; nt < 2; ++nt) {
    int n = cb0 + wave * 32 + nt * 16 + l16;
    float bv = bias[n];
#pragma unroll
    for (int mt = 0; mt < 4; ++mt) {
#pragma unroll
      for (int r = 0; r < 4; ++r) {
        int m = row0 + mt * 16 + quad * 4 + r;
        if (m < NNODES) {
          float v = acc[mt][nt][r] + bv;
          if (RELU) v = fmaxf(v, 0.0f);
          if (OUTF16) ((_Float16*)Yv)[(size_t)m * NTOT + n] = (_Float16)v;
          else ((float*)Yv)[(size_t)m * NTOT + n] = v;
        }
      }
    }
  }
}

// Final 256 -> 4 projection.
__global__ __launch_bounds__(256) void final_kernel(
    const float* __restrict__ X, const float* __restrict__ W,
    const float* __restrict__ b, float* __restrict__ out) {
  __shared__ float as[64][65];
  __shared__ float ws3[256][4];
  __shared__ float bs[4];
  const int tid = threadIdx.x;
  const int row0 = blockIdx.x * 64;
  for (int idx = tid; idx < 256 * 4; idx += 256) ws3[idx >> 2][idx & 3] = W[idx];
  if (tid < 4) bs[tid] = b[tid];
  const int r = tid >> 2, c = tid & 3;
  float acc = 0.0f;
  for (int k0 = 0; k0 < 256; k0 += 64) {
    __syncthreads();
    for (int idx = tid; idx < 64 * 64; idx += 256) {
      int r2 = idx >> 6, k = idx & 63;
      int rr = row0 + r2; if (rr >= NNODES) rr = NNODES - 1;
      as[r2][k] = X[(size_t)rr * 256 + k0 + k];
    }
    __syncthreads();
#pragma unroll
    for (int kk = 0; kk < 64; ++kk) acc = fmaf(as[r][kk], ws3[k0 + kk][c], acc);
  }
  int rr = row0 + r;
  if (rr < NNODES) out[(size_t)rr * 4 + c] = acc + bs[c];
}

extern "C" void kernel_launch(void* const* d_in, const int* in_sizes, int n_in,
                              void* d_out, int out_size, void* d_ws, size_t ws_size,
                              hipStream_t stream) {
  const float* x = (const float*)d_in[0];
  const int* eidx = (const int*)d_in[1];  // int32
  const float* w1a = (const float*)d_in[3];
  const float* b1a = (const float*)d_in[4];
  const float* w1b = (const float*)d_in[5];
  const float* b1b = (const float*)d_in[6];
  const float* w2a = (const float*)d_in[7];
  const float* b2a = (const float*)d_in[8];
  const float* w2b = (const float*)d_in[9];
  const float* b2b = (const float*)d_in[10];
  const float* w3a = (const float*)d_in[11];
  const float* b3a = (const float*)d_in[12];
  const float* w3b = (const float*)d_in[13];
  const float* b3b = (const float*)d_in[14];
  const float* wm1 = (const float*)d_in[15];
  const float* bm1 = (const float*)d_in[16];
  const float* wm2 = (const float*)d_in[17];
  const float* bm2 = (const float*)d_in[18];
  const float* wm3 = (const float*)d_in[19];
  const float* bm3 = (const float*)d_in[20];
  float* out = (float*)d_out;

  // Workspace layout in halves:
  // hcat_h[N*448] | Ph[N*256] | Qh[N*256] | agg[N*256 u32] | sedge[E u32]
  //   | wm1h[448*512] | w2d/w2b[64*128 ea] | w3d/w3b[128*256 ea]     (~91 MB)
  // Overlays: deg/cur on agg (CSR build, pre-agg-init); mh1h (f16 N*512) on agg;
  // mh2 (fp32 N*256) on Ph+Qh. Edge frag weights + wm2h in d_out (434 KB).
  _Float16* wsh = (_Float16*)d_ws;
  _Float16* hcat_h = wsh;
  _Float16* Ph = wsh + (size_t)NNODES * 448;
  _Float16* Qh = Ph + (size_t)NNODES * 256;
  unsigned* agg = (unsigned*)(Qh + (size_t)NNODES * 256);
  unsigned* sedge = agg + (size_t)NNODES * 256;
  _Float16* wm1h = (_Float16*)(sedge + NEDGES);
  _Float16* w2pd = wm1h + 448 * 512;
  _Float16* w2pb = w2pd + 64 * 128;
  _Float16* w3pd = w2pb + 64 * 128;
  _Float16* w3pb = w3pd + 128 * 256;
  int* deg = (int*)agg;
  int* cur = deg + NNODES;
  _Float16* mh1h = (_Float16*)agg;
  float* mh2 = (float*)Ph;
  _Float16* w1f = (_Float16*)d_out;        // 64*64   = 4096 halves
  _Float16* w2f = w1f + 4096;              // 128*128 = 16384
  _Float16* w3f = w2f + 16384;             // 256*256 = 65536
  _Float16* wm2h = w3f + 65536;            // 256*512 = 131072 -> total 434 KB

  const int ROWB64 = (NNODES + 63) / 64;     // 469
  const int EB = (NEDGES + 255) / 256;

  // ---- Build dst-sorted edge list (CSR order), reused by all 3 layers
  fill_u32<<<(NNODES + 255) / 256, 256, 0, stream>>>((unsigned*)deg, NNODES, 0u);
  hist_kernel<<<EB, 256, 0, stream>>>(eidx, deg);
  scan_kernel<<<1, 1024, 0, stream>>>(deg, cur);
  scatter_kernel<<<EB, 256, 0, stream>>>(eidx, cur, sedge);
  // ---- fragment-ordered f16 weights
  cvt_bfrag<<<(64 * 64 + 255) / 256, 256, 0, stream>>>(w1b, w1f, 64);
  cvt_bfrag<<<(128 * 128 + 255) / 256, 256, 0, stream>>>(w2b, w2f, 128);
  cvt_bfrag<<<(256 * 256 + 255) / 256, 256, 0, stream>>>(w3b, w3f, 256);
  cvt_pqfrag<<<(64 * 128 + 255) / 256, 256, 0, stream>>>(w2a, w2pd, w2pb, 64, 128);
  cvt_pqfrag<<<(128 * 256 + 255) / 256, 256, 0, stream>>>(w3a, w3pd, w3pb, 128, 256);
  cvt_wT<<<(448 * 512 + 255) / 256, 256, 0, stream>>>(wm1, wm1h, 448, 512);
  cvt_wT<<<(512 * 256 + 255) / 256, 256, 0, stream>>>(wm2, wm2h, 512, 256);

  // ---- EdgeConv 1: C=3 -> 64
  {
    int total = NNODES * 64;
    fill_u32<<<(total + 255) / 256, 256, 0, stream>>>(agg, total, ENC_NEGINF);
    pq_kernel<3, 64><<<dim3(ROWB64, 1), 256, 0, stream>>>(x, 3, w1a, b1a, Ph, Qh);
    edge_mfma<64><<<NEDGES / 64, 256, 0, stream>>>(sedge, Ph, Qh, w1f, b1b, agg);
    decode_kernel<<<(total + 255) / 256, 256, 0, stream>>>(agg, hcat_h + 0, 6, total);
  }
  // ---- EdgeConv 2: C=64 -> 128
  {
    int total = NNODES * 128;
    fill_u32<<<(total + 255) / 256, 256, 0, stream>>>(agg, total, ENC_NEGINF);
    pq_mfma<64, 128><<<dim3(ROWB64, 1), 256, 0, stream>>>(hcat_h, 0, w2pd, w2pb, b2a, Ph, Qh);
    edge_mfma<128><<<NEDGES / 64, 256, 0, stream>>>(sedge, Ph, Qh, w2f, b2b, agg);
    decode_kernel<<<(total + 255) / 256, 256, 0, stream>>>(agg, hcat_h + 64, 7, total);
  }
  // ---- EdgeConv 3: C=128 -> 256
  {
    int total = NNODES * 256;
    fill_u32<<<(total + 255) / 256, 256, 0, stream>>>(agg, total, ENC_NEGINF);
    pq_mfma<128, 256><<<dim3(ROWB64, 2), 256, 0, stream>>>(hcat_h, 64, w3pd, w3pb, b3a, Ph, Qh);
    edge_mfma<256><<<NEDGES / 64, 256, 0, stream>>>(sedge, Ph, Qh, w3f, b3b, agg);
    decode_kernel<<<(total + 255) / 256, 256, 0, stream>>>(agg, hcat_h + 192, 8, total);
  }
  // ---- MLP head (MFMA f16)
  mlp_mfma<448, 512, true, true><<<dim3(ROWB64, 4), 256, 0, stream>>>(hcat_h, wm1h, bm1, mh1h);
  mlp_mfma<512, 256, true, false><<<dim3(ROWB64, 2), 256, 0, stream>>>(mh1h, wm2h, bm2, mh2);
  final_kernel<<<ROWB64, 256, 0, stream>>>(mh2, wm3, bm3, out);
}